// Round 3
// baseline (2412.001 us; speedup 1.0000x reference)
//
#include <hip/hip_runtime.h>
#include <math.h>

#define NB 256
#define NS 64
#define NH 128
#define NZ 128
#define NSTEPS 63
#define PITCH 132  // preA/preP row pitch

// +4 floats of pad per 32-float chunk: chunk q starts at 36q -> distinct banks per q
__device__ __forceinline__ int padh(int i) { return i + ((i >> 5) << 2); }

// fast tanh for the non-recurrent score paths (C/G): v_exp + v_rcp, ~1e-7 abs err
__device__ __forceinline__ float ftanh(float x) {
  float e = __expf(2.0f * x);
  return 1.0f - 2.0f * __builtin_amdgcn_rcpf(e + 1.0f);
}

// pin 8 scalar floats into VGPRs (asm results can't be rematerialized from
// memory, so the allocator must keep them live in registers)
#define PIN8(a, i)                                                        \
  asm volatile("" : "+v"((a)[(i)]), "+v"((a)[(i) + 1]), "+v"((a)[(i) + 2]), \
                    "+v"((a)[(i) + 3]), "+v"((a)[(i) + 4]),               \
                    "+v"((a)[(i) + 5]), "+v"((a)[(i) + 6]),               \
                    "+v"((a)[(i) + 7]))

struct SM {
  float preA[NS * PITCH];  // IH @ W_a[:H]   (per-b)
  float preP[NS * PITCH];  // IH @ Wp[:H]    (per-b)
  float hbuf[2][144];      // ping-pong h, padded layout
  float atth[144];         // padded
  float ptrh[144];         // padded
  float va[144];           // padded
  float vpv[144];          // padded
  float fcop[144];         // padded
  float ctx[NH];
  float fc1[2 * NH];
  float zw1[2 * NH];       // Z @ W1[H:H+ZD] (per-b)
  float Gpre[3 * 384];     // [W_emb;b_emb] @ W_ih^T (+b_ih)
  float E1ref[3 * 256];    // [W_emb;b_emb] @ W1[2H:3H] (+b1)
  float bhh[384];
  float b2s[NH];
  float attn[NS];
  float maskv[NS];
  float inst[2 * NS];      // instance[b] cached (refin updates)
  int   sol[NS];           // solution[b] cached
  float red[2048];         // partial-reduction scratch (E1/E2) + scores
  float refin[4];
};

// launch_bounds(512, 1): grid == 256 blocks == #CUs, so only 1 block/CU ever
// runs. min-waves-per-EU=1 lifts the VGPR cap to 256 for a 512-thread block,
// letting the 176 persistent weight registers actually stay resident instead
// of being re-loaded (column-strided!) every step — round 1's regression.
__global__ __launch_bounds__(512, 1) void decoder_kernel(
    const float* __restrict__ instance, const int* __restrict__ solution,
    const float* __restrict__ Z, const float* __restrict__ IH,
    const float* __restrict__ last_hh, const float* __restrict__ W_emb,
    const float* __restrict__ b_emb, const float* __restrict__ W_ih,
    const float* __restrict__ W_hh, const float* __restrict__ b_ih,
    const float* __restrict__ b_hh, const float* __restrict__ W_a,
    const float* __restrict__ v_a, const float* __restrict__ W1,
    const float* __restrict__ b1, const float* __restrict__ W2,
    const float* __restrict__ b2, const float* __restrict__ Wp,
    const float* __restrict__ vp, float* __restrict__ out) {
  extern __shared__ float smraw[];
  SM& sm = *reinterpret_cast<SM*>(smraw);
  const int b = blockIdx.x;
  const int t = threadIdx.x;
  const float* ihb = IH + b * NS * NH;

  // ---------- thread-role constants ----------
  const int o4 = t >> 2, q4 = t & 3;          // quad layout: 128 outs x 4 k-chunks (intra-wave)
  const int s8 = t >> 3, q8 = t & 7;          // octet layout: 64 rows x 8 k-chunks (C,G)
  const int po8 = 16 * q8 + ((q8 >> 1) << 2); // padded base of 16-float chunk q8
  const int ob = (t & 31) * 4, qB = t >> 5;   // E2 partials (streamed)
  const int oE1 = (t & 63) * 4, qE1 = t >> 6; // E1 partials (streamed)

  // ---------- persistent register-cached weights (scalar arrays: pinnable) ----------
  float whr[32], whz[32], whn[32];  // W_hh rows o4 (r,z,n), cols [32q4,32q4+32)
  {
    const float* br = W_hh + (0 * NH + o4) * NH + 32 * q4;
    const float* bz = W_hh + (1 * NH + o4) * NH + 32 * q4;
    const float* bn = W_hh + (2 * NH + o4) * NH + 32 * q4;
#pragma unroll
    for (int j = 0; j < 8; ++j) {
      float4 r4 = *(const float4*)(br + 4 * j);
      float4 z4 = *(const float4*)(bz + 4 * j);
      float4 n4 = *(const float4*)(bn + 4 * j);
      whr[4 * j] = r4.x; whr[4 * j + 1] = r4.y; whr[4 * j + 2] = r4.z; whr[4 * j + 3] = r4.w;
      whz[4 * j] = z4.x; whz[4 * j + 1] = z4.y; whz[4 * j + 2] = z4.z; whz[4 * j + 3] = z4.w;
      whn[4 * j] = n4.x; whn[4 * j + 1] = n4.y; whn[4 * j + 2] = n4.z; whn[4 * j + 3] = n4.w;
    }
  }
  float wa2r[32], wpr[32];  // W_a[H+k][o4], Wp[H+k][o4] for k in [32q4,32q4+32)
#pragma unroll
  for (int k = 0; k < 32; ++k) wa2r[k] = W_a[(NH + 32 * q4 + k) * NH + o4];
#pragma unroll
  for (int k = 0; k < 32; ++k) wpr[k] = Wp[(NH + 32 * q4 + k) * NH + o4];
  float ihr[16];  // IH[s][o4] for s in [16q4,16q4+16)
#pragma unroll
  for (int s = 0; s < 16; ++s) ihr[s] = ihb[(16 * q4 + s) * NH + o4];

  PIN8(whr, 0); PIN8(whr, 8); PIN8(whr, 16); PIN8(whr, 24);
  PIN8(whz, 0); PIN8(whz, 8); PIN8(whz, 16); PIN8(whz, 24);
  PIN8(whn, 0); PIN8(whn, 8); PIN8(whn, 16); PIN8(whn, 24);
  PIN8(wa2r, 0); PIN8(wa2r, 8); PIN8(wa2r, 16); PIN8(wa2r, 24);
  PIN8(wpr, 0); PIN8(wpr, 8); PIN8(wpr, 16); PIN8(wpr, 24);
  PIN8(ihr, 0); PIN8(ihr, 8);

  // ---------- startup: fill LDS ----------
  if (t < NS) {
    sm.maskv[t] = 1.0f;
    sm.sol[t] = solution[b * NS + t];
  }
  if (t < 2 * NS) sm.inst[t] = instance[b * 2 * NS + t];
  if (t < NH) {
    sm.hbuf[0][padh(t)] = last_hh[b * NH + t];
    sm.b2s[t] = b2[t];
    sm.va[padh(t)] = v_a[t];
    sm.vpv[padh(t)] = vp[t];
  }
  if (t < 384) sm.bhh[t] = b_hh[t];
  // zw1[o] = Z[b] . W1[H:H+ZD, o]
  if (t < 256) {
    const float* zb = Z + b * NZ;
    float a0 = 0.f, a1 = 0.f;
#pragma unroll 4
    for (int k = 0; k < NZ; k += 2) {
      a0 += zb[k] * W1[(NH + k) * 256 + t];
      a1 += zb[k + 1] * W1[(NH + k + 1) * 256 + t];
    }
    sm.zw1[t] = a0 + a1;
  }
  // Gpre[c][o3] = [W_emb;b_emb][c] . W_ih[o3,:]  (+ b_ih for c=2)
  if (t < 384) {
    const float* wi = W_ih + t * NH;
    float g0 = 0.f, g1 = 0.f, g2 = 0.f;
#pragma unroll 4
    for (int k4 = 0; k4 < 32; ++k4) {
      float4 w = *(const float4*)(wi + 4 * k4);
      float4 e0 = *(const float4*)(W_emb + 4 * k4);
      float4 e1 = *(const float4*)(W_emb + NH + 4 * k4);
      float4 eb = *(const float4*)(b_emb + 4 * k4);
      g0 += w.x * e0.x + w.y * e0.y + w.z * e0.z + w.w * e0.w;
      g1 += w.x * e1.x + w.y * e1.y + w.z * e1.z + w.w * e1.w;
      g2 += w.x * eb.x + w.y * eb.y + w.z * eb.z + w.w * eb.w;
    }
    sm.Gpre[t] = g0;
    sm.Gpre[384 + t] = g1;
    sm.Gpre[768 + t] = g2 + b_ih[t];
  }
  // E1ref[c][o] = [W_emb;b_emb][c] . W1[2H+k, o]  (+ b1 for c=2)
  if (t < 256) {
    float e0 = 0.f, e1 = 0.f, e2 = 0.f;
#pragma unroll 4
    for (int k = 0; k < NH; ++k) {
      float w = W1[(256 + k) * 256 + t];
      e0 += W_emb[k] * w;
      e1 += W_emb[NH + k] * w;
      e2 += b_emb[k] * w;
    }
    sm.E1ref[t] = e0;
    sm.E1ref[256 + t] = e1;
    sm.E1ref[512 + t] = e2 + b1[t];
  }
  // preA / preP
  for (int o = t; o < NS * NH; o += 512) {
    int s = o >> 7, j = o & 127;
    const float* row = ihb + s * NH;
    float a0 = 0.f, a1 = 0.f, p0 = 0.f, p1 = 0.f;
#pragma unroll 4
    for (int k = 0; k < NH; k += 2) {
      float r0 = row[k], r1 = row[k + 1];
      a0 += r0 * W_a[k * NH + j];
      a1 += r1 * W_a[(k + 1) * NH + j];
      p0 += r0 * Wp[k * NH + j];
      p1 += r1 * Wp[(k + 1) * NH + j];
    }
    sm.preA[s * PITCH + j] = a0 + a1;
    sm.preP[s * PITCH + j] = p0 + p1;
  }
  __syncthreads();
  if (t == 0) {
    int s0 = sm.sol[0];
    sm.maskv[s0] = 0.0f;
    sm.refin[0] = sm.inst[2 * s0];
    sm.refin[1] = sm.inst[2 * s0 + 1];
    out[b * NS] = (float)s0;
  }

  // ---------- 63 sequential decode steps ----------
  int cur = 0;
  for (int step = 1; step <= NSTEPS; ++step) {
    __syncthreads();
    // A: gh = W_hh @ h (reg weights), quad-shfl reduce, gates fused -> hbuf[cur^1]
    {
      float ar = 0.f, az = 0.f, an = 0.f;
      const float* hp = sm.hbuf[cur] + 36 * q4;
#pragma unroll
      for (int j = 0; j < 8; ++j) {
        float4 hv = *(const float4*)(hp + 4 * j);
        ar += hv.x * whr[4 * j] + hv.y * whr[4 * j + 1] +
              hv.z * whr[4 * j + 2] + hv.w * whr[4 * j + 3];
        az += hv.x * whz[4 * j] + hv.y * whz[4 * j + 1] +
              hv.z * whz[4 * j + 2] + hv.w * whz[4 * j + 3];
        an += hv.x * whn[4 * j] + hv.y * whn[4 * j + 1] +
              hv.z * whn[4 * j + 2] + hv.w * whn[4 * j + 3];
      }
      ar += __shfl_xor(ar, 1); ar += __shfl_xor(ar, 2);
      az += __shfl_xor(az, 1); az += __shfl_xor(az, 2);
      an += __shfl_xor(an, 1); an += __shfl_xor(an, 2);
      if (q4 == 0) {
        float ghr = ar + sm.bhh[o4];
        float ghz = az + sm.bhh[NH + o4];
        float ghn = an + sm.bhh[2 * NH + o4];
        float r0 = sm.refin[0], r1 = sm.refin[1];
        float gir = r0 * sm.Gpre[o4] + r1 * sm.Gpre[384 + o4] + sm.Gpre[768 + o4];
        float giz = r0 * sm.Gpre[NH + o4] + r1 * sm.Gpre[384 + NH + o4] + sm.Gpre[768 + NH + o4];
        float gin = r0 * sm.Gpre[2 * NH + o4] + r1 * sm.Gpre[384 + 2 * NH + o4] + sm.Gpre[768 + 2 * NH + o4];
        // recurrent path keeps libm precision (h feeds back 63 steps)
        float r = 1.f / (1.f + expf(-(gir + ghr)));
        float z = 1.f / (1.f + expf(-(giz + ghz)));
        float n = tanhf(gin + r * ghn);
        float hold = sm.hbuf[cur][padh(o4)];
        sm.hbuf[cur ^ 1][padh(o4)] = (1.f - z) * n + z * hold;
      }
    }
    __syncthreads();
    // B: atth = h @ W_a[H:] (reg weights), quad-shfl
    {
      float acc = 0.f;
      const float* hp = sm.hbuf[cur ^ 1] + 36 * q4;
#pragma unroll
      for (int j = 0; j < 8; ++j) {
        float4 hv = *(const float4*)(hp + 4 * j);
        acc += hv.x * wa2r[4 * j] + hv.y * wa2r[4 * j + 1] +
               hv.z * wa2r[4 * j + 2] + hv.w * wa2r[4 * j + 3];
      }
      acc += __shfl_xor(acc, 1); acc += __shfl_xor(acc, 2);
      if (q4 == 0) sm.atth[padh(o4)] = acc;
    }
    __syncthreads();
    // C: attention tanh-dot, octet-shfl reduce -> red[s]
    {
      const float* pa = sm.preA + s8 * PITCH + 16 * q8;
      const float* ah = sm.atth + po8;
      const float* vv = sm.va + po8;
      float acc = 0.f;
#pragma unroll
      for (int u = 0; u < 4; ++u) {
        float4 a = *(const float4*)(pa + 4 * u);
        float4 hh = *(const float4*)(ah + 4 * u);
        float4 vw = *(const float4*)(vv + 4 * u);
        acc += ftanh(a.x + hh.x) * vw.x + ftanh(a.y + hh.y) * vw.y +
               ftanh(a.z + hh.z) * vw.z + ftanh(a.w + hh.w) * vw.w;
      }
      acc += __shfl_xor(acc, 1); acc += __shfl_xor(acc, 2); acc += __shfl_xor(acc, 4);
      if (q8 == 0) sm.red[s8] = acc;
    }
    __syncthreads();
    // softmax over s (wave 0)
    if (t < NS) {
      float e = sm.red[t];
      float m = e;
#pragma unroll
      for (int off = 32; off > 0; off >>= 1) m = fmaxf(m, __shfl_xor(m, off));
      float p = __expf(e - m);
      float ssum = p;
#pragma unroll
      for (int off = 32; off > 0; off >>= 1) ssum += __shfl_xor(ssum, off);
      sm.attn[t] = p / ssum;
    }
    __syncthreads();
    // D: ctx = attn @ IH (reg-cached IH), quad-shfl
    {
      float acc = 0.f;
      const float* ap = sm.attn + 16 * q4;
#pragma unroll
      for (int g = 0; g < 4; ++g) {
        float4 av = *(const float4*)(ap + 4 * g);
        acc += av.x * ihr[4 * g] + av.y * ihr[4 * g + 1] +
               av.z * ihr[4 * g + 2] + av.w * ihr[4 * g + 3];
      }
      acc += __shfl_xor(acc, 1); acc += __shfl_xor(acc, 2);
      if (q4 == 0) sm.ctx[o4] = acc;
    }
    __syncthreads();
    // E1: fc1 partials = ctx @ W1[:H] (streamed; L2-resident shared 131KB)
    {
      float4 acc = {0.f, 0.f, 0.f, 0.f};
      const float* w1p = W1 + (16 * qE1) * 256 + oE1;
#pragma unroll
      for (int k4 = 0; k4 < 4; ++k4) {
        float4 cv = *(const float4*)(sm.ctx + 16 * qE1 + 4 * k4);
        float cs[4] = {cv.x, cv.y, cv.z, cv.w};
#pragma unroll
        for (int u = 0; u < 4; ++u) {
          float4 w = *(const float4*)(w1p + (4 * k4 + u) * 256);
          acc.x += cs[u] * w.x; acc.y += cs[u] * w.y;
          acc.z += cs[u] * w.z; acc.w += cs[u] * w.w;
        }
      }
      *(float4*)(sm.red + qE1 * 256 + oE1) = acc;
    }
    __syncthreads();
    if (t < 256) {  // E1sum (+ zw1 + refh@W1ref via E1ref)
      float s = 0.f;
#pragma unroll
      for (int q = 0; q < 8; ++q) s += sm.red[q * 256 + t];
      float r0 = sm.refin[0], r1 = sm.refin[1];
      sm.fc1[t] = s + sm.zw1[t] + r0 * sm.E1ref[t] + r1 * sm.E1ref[256 + t] + sm.E1ref[512 + t];
    }
    __syncthreads();
    // E2: fco partials = fc1 @ W2 (streamed; L2-resident shared 131KB)
    {
      float4 acc = {0.f, 0.f, 0.f, 0.f};
      const float* w2p = W2 + (16 * qB) * NH + ob;
#pragma unroll
      for (int k4 = 0; k4 < 4; ++k4) {
        float4 fv = *(const float4*)(sm.fc1 + 16 * qB + 4 * k4);
        float fs[4] = {fv.x, fv.y, fv.z, fv.w};
#pragma unroll
        for (int u = 0; u < 4; ++u) {
          float4 w = *(const float4*)(w2p + (4 * k4 + u) * NH);
          acc.x += fs[u] * w.x; acc.y += fs[u] * w.y;
          acc.z += fs[u] * w.z; acc.w += fs[u] * w.w;
        }
      }
      *(float4*)(sm.red + qB * NH + ob) = acc;
    }
    __syncthreads();
    if (t < NH) {  // E2sum -> padded fco
      float s = 0.f;
#pragma unroll
      for (int q = 0; q < 16; ++q) s += sm.red[q * NH + t];
      sm.fcop[padh(t)] = s + sm.b2s[t];
    }
    __syncthreads();
    // F: ptrh = fco @ Wp[H:] (reg weights), quad-shfl
    {
      float acc = 0.f;
      const float* fp = sm.fcop + 36 * q4;
#pragma unroll
      for (int j = 0; j < 8; ++j) {
        float4 fv = *(const float4*)(fp + 4 * j);
        acc += fv.x * wpr[4 * j] + fv.y * wpr[4 * j + 1] +
               fv.z * wpr[4 * j + 2] + fv.w * wpr[4 * j + 3];
      }
      acc += __shfl_xor(acc, 1); acc += __shfl_xor(acc, 2);
      if (q4 == 0) sm.ptrh[padh(o4)] = acc;
    }
    __syncthreads();
    // G: pointer tanh-dot, octet-shfl reduce -> red[s]
    {
      const float* pp = sm.preP + s8 * PITCH + 16 * q8;
      const float* ph = sm.ptrh + po8;
      const float* vv = sm.vpv + po8;
      float acc = 0.f;
#pragma unroll
      for (int u = 0; u < 4; ++u) {
        float4 a = *(const float4*)(pp + 4 * u);
        float4 hh = *(const float4*)(ph + 4 * u);
        float4 vw = *(const float4*)(vv + 4 * u);
        acc += ftanh(a.x + hh.x) * vw.x + ftanh(a.y + hh.y) * vw.y +
               ftanh(a.z + hh.z) * vw.z + ftanh(a.w + hh.w) * vw.w;
      }
      acc += __shfl_xor(acc, 1); acc += __shfl_xor(acc, 2); acc += __shfl_xor(acc, 4);
      if (q8 == 0) sm.red[s8] = acc;
    }
    __syncthreads();
    // H: masked log-softmax, argmax (first-index tie), outputs, state update
    if (t < NS) {
      float lg = sm.red[t];
      float ml = (sm.maskv[t] > 0.5f) ? lg : -INFINITY;
      float m = ml;
      int mi = t;
#pragma unroll
      for (int off = 32; off > 0; off >>= 1) {
        float om = __shfl_xor(m, off);
        int oi = __shfl_xor(mi, off);
        if (om > m || (om == m && oi < mi)) { m = om; mi = oi; }
      }
      float p = __expf(ml - m);
      float ssum = p;
#pragma unroll
      for (int off = 32; off > 0; off >>= 1) ssum += __shfl_xor(ssum, off);
      int ptr = sm.sol[step];
      float pv = __shfl(ml, ptr);
      if (t == 0) {
        out[b * NS + step] = (float)mi;
        out[NB * NS + b * NSTEPS + (step - 1)] = pv - m - __logf(ssum);
        sm.maskv[ptr] = 0.0f;
        sm.refin[0] = sm.inst[2 * ptr];
        sm.refin[1] = sm.inst[2 * ptr + 1];
      }
    }
    cur ^= 1;
  }
}

extern "C" void kernel_launch(void* const* d_in, const int* in_sizes, int n_in,
                              void* d_out, int out_size, void* d_ws,
                              size_t ws_size, hipStream_t stream) {
  (void)in_sizes; (void)n_in; (void)out_size; (void)d_ws; (void)ws_size;
  const float* instance = (const float*)d_in[0];
  const int*   solution = (const int*)d_in[1];
  const float* Z        = (const float*)d_in[2];
  const float* IH       = (const float*)d_in[3];
  const float* last_hh  = (const float*)d_in[4];
  const float* W_emb    = (const float*)d_in[5];
  const float* b_emb    = (const float*)d_in[6];
  const float* W_ih     = (const float*)d_in[7];
  const float* W_hh     = (const float*)d_in[8];
  const float* b_ih     = (const float*)d_in[9];
  const float* b_hh     = (const float*)d_in[10];
  const float* W_a      = (const float*)d_in[11];
  const float* v_a      = (const float*)d_in[12];
  const float* W1       = (const float*)d_in[13];
  const float* b1       = (const float*)d_in[14];
  const float* W2       = (const float*)d_in[15];
  const float* b2       = (const float*)d_in[16];
  const float* Wp       = (const float*)d_in[17];
  const float* vp       = (const float*)d_in[18];
  float* out = (float*)d_out;

  const int shmem = (int)sizeof(SM);
  static_assert(sizeof(SM) <= 160 * 1024, "LDS overlay too big");
  hipFuncSetAttribute((const void*)decoder_kernel,
                      hipFuncAttributeMaxDynamicSharedMemorySize, shmem);
  decoder_kernel<<<NB, 512, shmem, stream>>>(
      instance, solution, Z, IH, last_hh, W_emb, b_emb, W_ih, W_hh, b_ih, b_hh,
      W_a, v_a, W1, b1, W2, b2, Wp, vp, out);
}

// Round 4
// 1380.944 us; speedup vs baseline: 1.7466x; 1.7466x over previous
//
#include <hip/hip_runtime.h>
#include <math.h>

#define NB 256
#define NS 64
#define NH 128
#define NZ 128
#define NSTEPS 63
#define PITCH 132  // preA/preP row pitch: 16B-aligned, 4-way bank alias max

// fast tanh for the non-recurrent score paths (C/G): v_exp + v_rcp, ~1e-7 abs err
// (validated round 1: passed with absmax 0.0)
__device__ __forceinline__ float ftanh(float x) {
  float e = __expf(2.0f * x);
  return 1.0f - 2.0f * __builtin_amdgcn_rcpf(e + 1.0f);
}

struct SM {
  float preA[NS * PITCH];  // IH @ W_a[:H]   (per-b)
  float preP[NS * PITCH];  // IH @ Wp[:H]    (per-b)
  float Wa2[NH * NH];      // W_a[H+k][o] = Wa2[k*128+o]  (shared weights, LDS)
  float hbuf[2][NH];       // ping-pong h (fused gates write nxt while others read cur)
  float atth[NH];
  float ctx[NH];
  float fc1[2 * NH];
  float fco[NH];
  float ptrh[NH];
  float zw1[2 * NH];       // Z @ W1[H:H+ZD] (per-b)
  float Gpre[3 * 384];     // [W_emb;b_emb] @ W_ih^T (+b_ih)
  float E1ref[3 * 256];    // [W_emb;b_emb] @ W1[2H:3H] (+b1)
  float bhh[384];
  float b2s[NH];
  float va[NH];
  float vpv[NH];
  float attn[NS];
  float maskv[NS];
  float inst[2 * NS];      // instance[b] cached in LDS (refin updates off critical global path)
  int   sol[NS];           // solution[b] cached in LDS
  float red[2048];         // generic partial-reduction scratch
  float refin[4];
};

// Round-0 proven codegen environment: (512,2). Persistent register request is
// exactly 96 floats (W_hh gate rows as float4[8]x3) -- fits the compiler's
// 128-VGPR choice without demotion. NO asm pins (r1/r3 lessons: the allocator
// rematerializes (r1, strided reloads) or spills to scratch (r3) when pushed).
__global__ __launch_bounds__(512, 2) void decoder_kernel(
    const float* __restrict__ instance, const int* __restrict__ solution,
    const float* __restrict__ Z, const float* __restrict__ IH,
    const float* __restrict__ last_hh, const float* __restrict__ W_emb,
    const float* __restrict__ b_emb, const float* __restrict__ W_ih,
    const float* __restrict__ W_hh, const float* __restrict__ b_ih,
    const float* __restrict__ b_hh, const float* __restrict__ W_a,
    const float* __restrict__ v_a, const float* __restrict__ W1,
    const float* __restrict__ b1, const float* __restrict__ W2,
    const float* __restrict__ b2, const float* __restrict__ Wp,
    const float* __restrict__ vp, float* __restrict__ out) {
  extern __shared__ float smraw[];
  SM& sm = *reinterpret_cast<SM*>(smraw);
  const int b = blockIdx.x;
  const int t = threadIdx.x;
  const float* ihb = IH + b * NS * NH;

  // ---------- thread-role constants ----------
  const int o4 = t >> 2, q4 = t & 3;          // phase A: 128 outs x 4 k-chunks (intra-wave quad)
  const int s8 = t >> 3, q8 = t & 7;          // phases C,G: 64 rows x 8 k-chunks (intra-wave octet)
  const int ob = (t & 31) * 4, qB = t >> 5;   // quad-out x 16 chunks (B,D,E2,F)
  const int oE1 = (t & 63) * 4, qE1 = t >> 6; // quad-out x 8 chunks (E1)

  // ---------- persistent register-cached weights: W_hh only (96 VGPRs) ----------
  float4 whr[8], whz[8], whn[8];  // W_hh rows o4 (r,z,n gates), cols [32q4, 32q4+32)
  {
    const float* br = W_hh + (0 * NH + o4) * NH + 32 * q4;
    const float* bz = W_hh + (1 * NH + o4) * NH + 32 * q4;
    const float* bn = W_hh + (2 * NH + o4) * NH + 32 * q4;
#pragma unroll
    for (int j = 0; j < 8; ++j) {
      whr[j] = *(const float4*)(br + 4 * j);
      whz[j] = *(const float4*)(bz + 4 * j);
      whn[j] = *(const float4*)(bn + 4 * j);
    }
  }

  // ---------- startup: fill LDS ----------
  if (t < NS) {
    sm.maskv[t] = 1.0f;
    sm.sol[t] = solution[b * NS + t];
  }
  if (t < 2 * NS) sm.inst[t] = instance[b * 2 * NS + t];
  if (t < NH) {
    sm.hbuf[0][t] = last_hh[b * NH + t];
    sm.b2s[t] = b2[t];
    sm.va[t] = v_a[t];
    sm.vpv[t] = vp[t];
  }
  if (t < 384) sm.bhh[t] = b_hh[t];
  for (int i = 4 * t; i < NH * NH; i += 2048)
    *(float4*)(sm.Wa2 + i) = *(const float4*)(W_a + NH * NH + i);
  // zw1[o] = Z[b] . W1[H:H+ZD, o]
  if (t < 256) {
    const float* zb = Z + b * NZ;
    float a0 = 0.f, a1 = 0.f;
#pragma unroll 4
    for (int k = 0; k < NZ; k += 2) {
      a0 += zb[k] * W1[(NH + k) * 256 + t];
      a1 += zb[k + 1] * W1[(NH + k + 1) * 256 + t];
    }
    sm.zw1[t] = a0 + a1;
  }
  // Gpre[c][o3] = [W_emb;b_emb][c] . W_ih[o3,:]  (+ b_ih for c=2)
  if (t < 384) {
    const float* wi = W_ih + t * NH;
    float g0 = 0.f, g1 = 0.f, g2 = 0.f;
#pragma unroll 4
    for (int k4 = 0; k4 < 32; ++k4) {
      float4 w = *(const float4*)(wi + 4 * k4);
      float4 e0 = *(const float4*)(W_emb + 4 * k4);
      float4 e1 = *(const float4*)(W_emb + NH + 4 * k4);
      float4 eb = *(const float4*)(b_emb + 4 * k4);
      g0 += w.x * e0.x + w.y * e0.y + w.z * e0.z + w.w * e0.w;
      g1 += w.x * e1.x + w.y * e1.y + w.z * e1.z + w.w * e1.w;
      g2 += w.x * eb.x + w.y * eb.y + w.z * eb.z + w.w * eb.w;
    }
    sm.Gpre[t] = g0;
    sm.Gpre[384 + t] = g1;
    sm.Gpre[768 + t] = g2 + b_ih[t];
  }
  // E1ref[c][o] = [W_emb;b_emb][c] . W1[2H+k, o]  (+ b1 for c=2)
  if (t < 256) {
    float e0 = 0.f, e1 = 0.f, e2 = 0.f;
#pragma unroll 4
    for (int k = 0; k < NH; ++k) {
      float w = W1[(256 + k) * 256 + t];
      e0 += W_emb[k] * w;
      e1 += W_emb[NH + k] * w;
      e2 += b_emb[k] * w;
    }
    sm.E1ref[t] = e0;
    sm.E1ref[256 + t] = e1;
    sm.E1ref[512 + t] = e2 + b1[t];
  }
  // preA / preP
  for (int o = t; o < NS * NH; o += 512) {
    int s = o >> 7, j = o & 127;
    const float* row = ihb + s * NH;
    float a0 = 0.f, a1 = 0.f, p0 = 0.f, p1 = 0.f;
#pragma unroll 4
    for (int k = 0; k < NH; k += 2) {
      float r0 = row[k], r1 = row[k + 1];
      a0 += r0 * W_a[k * NH + j];
      a1 += r1 * W_a[(k + 1) * NH + j];
      p0 += r0 * Wp[k * NH + j];
      p1 += r1 * Wp[(k + 1) * NH + j];
    }
    sm.preA[s * PITCH + j] = a0 + a1;
    sm.preP[s * PITCH + j] = p0 + p1;
  }
  __syncthreads();
  if (t == 0) {
    int s0 = sm.sol[0];
    sm.maskv[s0] = 0.0f;
    sm.refin[0] = sm.inst[2 * s0];
    sm.refin[1] = sm.inst[2 * s0 + 1];
    out[b * NS] = (float)s0;
  }

  // ---------- 63 sequential decode steps ----------
  int cur = 0;
  for (int step = 1; step <= NSTEPS; ++step) {
    const int nxt = cur ^ 1;
    __syncthreads();
    // A: gh = W_hh @ h (reg weights), intra-wave quad-shfl, gates fused -> hbuf[nxt]
    {
      float ar = 0.f, az = 0.f, an = 0.f;
      const float* hp = sm.hbuf[cur] + 32 * q4;
#pragma unroll
      for (int j = 0; j < 8; ++j) {
        float4 hv = *(const float4*)(hp + 4 * j);
        ar += hv.x * whr[j].x + hv.y * whr[j].y + hv.z * whr[j].z + hv.w * whr[j].w;
        az += hv.x * whz[j].x + hv.y * whz[j].y + hv.z * whz[j].z + hv.w * whz[j].w;
        an += hv.x * whn[j].x + hv.y * whn[j].y + hv.z * whn[j].z + hv.w * whn[j].w;
      }
      ar += __shfl_xor(ar, 1); ar += __shfl_xor(ar, 2);
      az += __shfl_xor(az, 1); az += __shfl_xor(az, 2);
      an += __shfl_xor(an, 1); an += __shfl_xor(an, 2);
      if (q4 == 0) {
        float ghr = ar + sm.bhh[o4];
        float ghz = az + sm.bhh[NH + o4];
        float ghn = an + sm.bhh[2 * NH + o4];
        float r0 = sm.refin[0], r1 = sm.refin[1];
        float gir = r0 * sm.Gpre[o4] + r1 * sm.Gpre[384 + o4] + sm.Gpre[768 + o4];
        float giz = r0 * sm.Gpre[NH + o4] + r1 * sm.Gpre[384 + NH + o4] + sm.Gpre[768 + NH + o4];
        float gin = r0 * sm.Gpre[2 * NH + o4] + r1 * sm.Gpre[384 + 2 * NH + o4] + sm.Gpre[768 + 2 * NH + o4];
        // recurrent path keeps libm precision (h feeds back 63 steps)
        float r = 1.f / (1.f + expf(-(gir + ghr)));
        float z = 1.f / (1.f + expf(-(giz + ghz)));
        float n = tanhf(gin + r * ghn);
        sm.hbuf[nxt][o4] = (1.f - z) * n + z * sm.hbuf[cur][o4];
      }
    }
    __syncthreads();
    // B: atth partials = h @ Wa2 (LDS weights), quad-out x 16 k-chunks
    {
      float4 acc = {0.f, 0.f, 0.f, 0.f};
      float4 h0 = *(const float4*)(sm.hbuf[nxt] + 8 * qB);
      float4 h1 = *(const float4*)(sm.hbuf[nxt] + 8 * qB + 4);
      float hk[8] = {h0.x, h0.y, h0.z, h0.w, h1.x, h1.y, h1.z, h1.w};
#pragma unroll
      for (int kk = 0; kk < 8; ++kk) {
        float4 w = *(const float4*)(sm.Wa2 + (8 * qB + kk) * NH + ob);
        acc.x += hk[kk] * w.x; acc.y += hk[kk] * w.y;
        acc.z += hk[kk] * w.z; acc.w += hk[kk] * w.w;
      }
      *(float4*)(sm.red + qB * NH + ob) = acc;
    }
    __syncthreads();
    if (t < NH) {  // Bsum
      float s = 0.f;
#pragma unroll
      for (int q = 0; q < 16; ++q) s += sm.red[q * NH + t];
      sm.atth[t] = s;
    }
    __syncthreads();
    // C: attention tanh-dot, octet-shfl reduce -> red[s]
    {
      const float* pa = sm.preA + s8 * PITCH + 16 * q8;
      const float* ah = sm.atth + 16 * q8;
      const float* vv = sm.va + 16 * q8;
      float acc = 0.f;
#pragma unroll
      for (int u = 0; u < 4; ++u) {
        float4 a = *(const float4*)(pa + 4 * u);
        float4 hh = *(const float4*)(ah + 4 * u);
        float4 vw = *(const float4*)(vv + 4 * u);
        acc += ftanh(a.x + hh.x) * vw.x + ftanh(a.y + hh.y) * vw.y +
               ftanh(a.z + hh.z) * vw.z + ftanh(a.w + hh.w) * vw.w;
      }
      acc += __shfl_xor(acc, 1); acc += __shfl_xor(acc, 2); acc += __shfl_xor(acc, 4);
      if (q8 == 0) sm.red[s8] = acc;
    }
    __syncthreads();
    // softmax over s (wave 0)
    if (t < NS) {
      float e = sm.red[t];
      float m = e;
#pragma unroll
      for (int off = 32; off > 0; off >>= 1) m = fmaxf(m, __shfl_xor(m, off));
      float p = __expf(e - m);
      float ssum = p;
#pragma unroll
      for (int off = 32; off > 0; off >>= 1) ssum += __shfl_xor(ssum, off);
      sm.attn[t] = p / ssum;
    }
    __syncthreads();
    // D: context partials (IH streamed from L2), quad-out x s-chunk 4
    {
      float4 acc = {0.f, 0.f, 0.f, 0.f};
      const float* ib = ihb + (4 * qB) * NH + ob;
      float4 av = *(const float4*)(sm.attn + 4 * qB);
      float as[4] = {av.x, av.y, av.z, av.w};
#pragma unroll
      for (int ss = 0; ss < 4; ++ss) {
        float4 x = *(const float4*)(ib + ss * NH);
        acc.x += as[ss] * x.x; acc.y += as[ss] * x.y;
        acc.z += as[ss] * x.z; acc.w += as[ss] * x.w;
      }
      *(float4*)(sm.red + qB * NH + ob) = acc;
    }
    __syncthreads();
    if (t < NH) {  // Dsum
      float s = 0.f;
#pragma unroll
      for (int q = 0; q < 16; ++q) s += sm.red[q * NH + t];
      sm.ctx[t] = s;
    }
    __syncthreads();
    // E1: fc1 partials = ctx @ W1[:H] (streamed from L2), quad-out x 8 k-chunks
    {
      float4 acc = {0.f, 0.f, 0.f, 0.f};
      const float* w1p = W1 + (16 * qE1) * 256 + oE1;
#pragma unroll
      for (int k4 = 0; k4 < 4; ++k4) {
        float4 cv = *(const float4*)(sm.ctx + 16 * qE1 + 4 * k4);
        float cs[4] = {cv.x, cv.y, cv.z, cv.w};
#pragma unroll
        for (int u = 0; u < 4; ++u) {
          float4 w = *(const float4*)(w1p + (4 * k4 + u) * 256);
          acc.x += cs[u] * w.x; acc.y += cs[u] * w.y;
          acc.z += cs[u] * w.z; acc.w += cs[u] * w.w;
        }
      }
      *(float4*)(sm.red + qE1 * 256 + oE1) = acc;
    }
    __syncthreads();
    if (t < 256) {  // E1sum (+ zw1 + refh@W1ref via E1ref)
      float s = 0.f;
#pragma unroll
      for (int q = 0; q < 8; ++q) s += sm.red[q * 256 + t];
      float r0 = sm.refin[0], r1 = sm.refin[1];
      sm.fc1[t] = s + sm.zw1[t] + r0 * sm.E1ref[t] + r1 * sm.E1ref[256 + t] + sm.E1ref[512 + t];
    }
    __syncthreads();
    // E2: fco partials = fc1 @ W2 (streamed from L2), quad-out x 16 k-chunks
    {
      float4 acc = {0.f, 0.f, 0.f, 0.f};
      const float* w2p = W2 + (16 * qB) * NH + ob;
#pragma unroll
      for (int k4 = 0; k4 < 4; ++k4) {
        float4 fv = *(const float4*)(sm.fc1 + 16 * qB + 4 * k4);
        float fs[4] = {fv.x, fv.y, fv.z, fv.w};
#pragma unroll
        for (int u = 0; u < 4; ++u) {
          float4 w = *(const float4*)(w2p + (4 * k4 + u) * NH);
          acc.x += fs[u] * w.x; acc.y += fs[u] * w.y;
          acc.z += fs[u] * w.z; acc.w += fs[u] * w.w;
        }
      }
      *(float4*)(sm.red + qB * NH + ob) = acc;
    }
    __syncthreads();
    if (t < NH) {  // E2sum
      float s = 0.f;
#pragma unroll
      for (int q = 0; q < 16; ++q) s += sm.red[q * NH + t];
      sm.fco[t] = s + sm.b2s[t];
    }
    __syncthreads();
    // F: ptrh partials = fco @ Wp[H:] (streamed from L2), quad-out x 16 k-chunks
    {
      float4 acc = {0.f, 0.f, 0.f, 0.f};
      const float* wpp = Wp + (NH + 8 * qB) * NH + ob;
      float4 f0 = *(const float4*)(sm.fco + 8 * qB);
      float4 f1 = *(const float4*)(sm.fco + 8 * qB + 4);
      float fs[8] = {f0.x, f0.y, f0.z, f0.w, f1.x, f1.y, f1.z, f1.w};
#pragma unroll
      for (int kk = 0; kk < 8; ++kk) {
        float4 w = *(const float4*)(wpp + kk * NH);
        acc.x += fs[kk] * w.x; acc.y += fs[kk] * w.y;
        acc.z += fs[kk] * w.z; acc.w += fs[kk] * w.w;
      }
      *(float4*)(sm.red + qB * NH + ob) = acc;
    }
    __syncthreads();
    if (t < NH) {  // Fsum
      float s = 0.f;
#pragma unroll
      for (int q = 0; q < 16; ++q) s += sm.red[q * NH + t];
      sm.ptrh[t] = s;
    }
    __syncthreads();
    // G: pointer tanh-dot, octet-shfl reduce -> red[s]
    {
      const float* pp = sm.preP + s8 * PITCH + 16 * q8;
      const float* ph = sm.ptrh + 16 * q8;
      const float* vv = sm.vpv + 16 * q8;
      float acc = 0.f;
#pragma unroll
      for (int u = 0; u < 4; ++u) {
        float4 a = *(const float4*)(pp + 4 * u);
        float4 hh = *(const float4*)(ph + 4 * u);
        float4 vw = *(const float4*)(vv + 4 * u);
        acc += ftanh(a.x + hh.x) * vw.x + ftanh(a.y + hh.y) * vw.y +
               ftanh(a.z + hh.z) * vw.z + ftanh(a.w + hh.w) * vw.w;
      }
      acc += __shfl_xor(acc, 1); acc += __shfl_xor(acc, 2); acc += __shfl_xor(acc, 4);
      if (q8 == 0) sm.red[s8] = acc;
    }
    __syncthreads();
    // H: masked log-softmax, argmax (first-index tie), outputs, state update
    if (t < NS) {
      float lg = sm.red[t];
      float ml = (sm.maskv[t] > 0.5f) ? lg : -INFINITY;
      float m = ml;
      int mi = t;
#pragma unroll
      for (int off = 32; off > 0; off >>= 1) {
        float om = __shfl_xor(m, off);
        int oi = __shfl_xor(mi, off);
        if (om > m || (om == m && oi < mi)) { m = om; mi = oi; }
      }
      float p = __expf(ml - m);
      float ssum = p;
#pragma unroll
      for (int off = 32; off > 0; off >>= 1) ssum += __shfl_xor(ssum, off);
      int ptr = sm.sol[step];
      float pv = __shfl(ml, ptr);
      if (t == 0) {
        out[b * NS + step] = (float)mi;
        out[NB * NS + b * NSTEPS + (step - 1)] = pv - m - __logf(ssum);
        sm.maskv[ptr] = 0.0f;
        sm.refin[0] = sm.inst[2 * ptr];
        sm.refin[1] = sm.inst[2 * ptr + 1];
      }
    }
    cur = nxt;
  }
}

extern "C" void kernel_launch(void* const* d_in, const int* in_sizes, int n_in,
                              void* d_out, int out_size, void* d_ws,
                              size_t ws_size, hipStream_t stream) {
  (void)in_sizes; (void)n_in; (void)out_size; (void)d_ws; (void)ws_size;
  const float* instance = (const float*)d_in[0];
  const int*   solution = (const int*)d_in[1];
  const float* Z        = (const float*)d_in[2];
  const float* IH       = (const float*)d_in[3];
  const float* last_hh  = (const float*)d_in[4];
  const float* W_emb    = (const float*)d_in[5];
  const float* b_emb    = (const float*)d_in[6];
  const float* W_ih     = (const float*)d_in[7];
  const float* W_hh     = (const float*)d_in[8];
  const float* b_ih     = (const float*)d_in[9];
  const float* b_hh     = (const float*)d_in[10];
  const float* W_a      = (const float*)d_in[11];
  const float* v_a      = (const float*)d_in[12];
  const float* W1       = (const float*)d_in[13];
  const float* b1       = (const float*)d_in[14];
  const float* W2       = (const float*)d_in[15];
  const float* b2       = (const float*)d_in[16];
  const float* Wp       = (const float*)d_in[17];
  const float* vp       = (const float*)d_in[18];
  float* out = (float*)d_out;

  const int shmem = (int)sizeof(SM);
  static_assert(sizeof(SM) <= 160 * 1024, "LDS overlay too big");
  hipFuncSetAttribute((const void*)decoder_kernel,
                      hipFuncAttributeMaxDynamicSharedMemorySize, shmem);
  decoder_kernel<<<NB, 512, shmem, stream>>>(
      instance, solution, Z, IH, last_hh, W_emb, b_emb, W_ih, W_hh, b_ih, b_hh,
      W_a, v_a, W1, b1, W2, b2, Wp, vp, out);
}

// Round 5
// 962.305 us; speedup vs baseline: 2.5065x; 1.4350x over previous
//
#include <hip/hip_runtime.h>
#include <math.h>

#define NB 256
#define NS 64
#define NH 128
#define NZ 128
#define NSTEPS 63
#define PITCH 132  // preA/preP/WfT row pitch: 16B-aligned, avoids power-of-2 bank alias

// +4 floats of pad per 32-float chunk (validated r1: conflicts 5.25e7 -> 6.2e6)
__device__ __forceinline__ int padh(int i) { return i + ((i >> 5) << 2); }

// fast tanh for the non-recurrent score paths (C/G): v_exp + v_rcp (validated r1/r4)
__device__ __forceinline__ float ftanh(float x) {
  float e = __expf(2.0f * x);
  return 1.0f - 2.0f * __builtin_amdgcn_rcpf(e + 1.0f);
}

struct SM {
  float preA[NS * PITCH];  // IH @ W_a[:H] (per-b). preA+preP double as S scratch at startup
  float preP[NS * PITCH];  // IH @ Wp[:H]  (per-b)
  float WfT[NH * PITCH];   // WfoldT[o][k] = (W1[:H]@W2@Wp[H:])^T  (shared, folded MLP)
  float red[2048];         // partial-reduction scratch; startup: am[768] + v[384]
  float Gpre[3 * 384];     // [W_emb;b_emb] @ W_ih^T (+b_ih)
  float bhh[384];
  float hbuf[2][144];      // ping-pong h, padded
  float atth[144];         // padded
  float ctx[144];          // padded
  float ptrh[144];         // padded
  float va[144];           // padded
  float vpv[144];          // padded
  float U[3 * NH];         // refin-affine fold: ptrh += r0*U0 + r1*U1 + U2
  float attn[NS];
  float maskv[NS];
  float inst[2 * NS];      // instance[b] cached in LDS
  int   sol[NS];           // solution[b] cached in LDS
  float refin[4];
};

// (512,2): r0/r4-proven codegen environment. Persistent register request is the
// 96-float W_hh cache only -- fits the compiler's 128-VGPR choice. No asm pins.
__global__ __launch_bounds__(512, 2) void decoder_kernel(
    const float* __restrict__ instance, const int* __restrict__ solution,
    const float* __restrict__ Z, const float* __restrict__ IH,
    const float* __restrict__ last_hh, const float* __restrict__ W_emb,
    const float* __restrict__ b_emb, const float* __restrict__ W_ih,
    const float* __restrict__ W_hh, const float* __restrict__ b_ih,
    const float* __restrict__ b_hh, const float* __restrict__ W_a,
    const float* __restrict__ v_a, const float* __restrict__ W1,
    const float* __restrict__ b1, const float* __restrict__ W2,
    const float* __restrict__ b2, const float* __restrict__ Wp,
    const float* __restrict__ vp, float* __restrict__ out) {
  extern __shared__ float smraw[];
  SM& sm = *reinterpret_cast<SM*>(smraw);
  const int b = blockIdx.x;
  const int t = threadIdx.x;
  const float* ihb = IH + b * NS * NH;

  // ---------- thread-role constants ----------
  const int o4 = t >> 2, q4 = t & 3;          // phases A,P: 128 outs x 4 k-chunks (intra-wave quad)
  const int s8 = t >> 3, q8 = t & 7;          // phases C,G: 64 rows x 8 k-chunks (intra-wave octet)
  const int po8 = padh(16 * q8);              // padded base of 16-float chunk q8
  const int ob = (t & 31) * 4, qB = t >> 5;   // quad-out x 16 chunks (B,D streamed partials)
  const int oS = t & 127, kqS = t >> 7;       // startup GEMM layout: 128 cols x 4 k-phases

  // ---------- persistent register-cached weights: W_hh only (96 VGPRs) ----------
  float4 whr[8], whz[8], whn[8];  // W_hh rows o4 (r,z,n gates), cols [32q4, 32q4+32)
  {
    const float* br = W_hh + (0 * NH + o4) * NH + 32 * q4;
    const float* bz = W_hh + (1 * NH + o4) * NH + 32 * q4;
    const float* bn = W_hh + (2 * NH + o4) * NH + 32 * q4;
#pragma unroll
    for (int j = 0; j < 8; ++j) {
      whr[j] = *(const float4*)(br + 4 * j);
      whz[j] = *(const float4*)(bz + 4 * j);
      whn[j] = *(const float4*)(bn + 4 * j);
    }
  }

  // ================= startup phase 0 =================
  if (t < NS) {
    sm.maskv[t] = 1.0f;
    sm.sol[t] = solution[b * NS + t];
  }
  if (t < 2 * NS) sm.inst[t] = instance[b * 2 * NS + t];
  if (t < NH) {
    sm.hbuf[0][padh(t)] = last_hh[b * NH + t];
    sm.va[padh(t)] = v_a[t];
    sm.vpv[padh(t)] = vp[t];
  }
  if (t < 384) sm.bhh[t] = b_hh[t];
  // Gpre[c][o3] = [W_emb;b_emb][c] . W_ih[o3,:]  (+ b_ih for c=2)
  if (t < 384) {
    const float* wi = W_ih + t * NH;
    float g0 = 0.f, g1 = 0.f, g2 = 0.f;
#pragma unroll 4
    for (int k4 = 0; k4 < 32; ++k4) {
      float4 w = *(const float4*)(wi + 4 * k4);
      float4 e0 = *(const float4*)(W_emb + 4 * k4);
      float4 e1 = *(const float4*)(W_emb + NH + 4 * k4);
      float4 eb = *(const float4*)(b_emb + 4 * k4);
      g0 += w.x * e0.x + w.y * e0.y + w.z * e0.z + w.w * e0.w;
      g1 += w.x * e1.x + w.y * e1.y + w.z * e1.z + w.w * e1.w;
      g2 += w.x * eb.x + w.y * eb.y + w.z * eb.z + w.w * eb.w;
    }
    sm.Gpre[t] = g0;
    sm.Gpre[384 + t] = g1;
    sm.Gpre[768 + t] = g2 + b_ih[t];
  }
  // am[c][m] (m<256): fc1 affine inputs. am2 folds zw1 (Z part), b_emb part and b1.
  if (t < 256) {
    const float* zb = Z + b * NZ;
    float a0 = 0.f, a1 = 0.f, a2 = 0.f;
#pragma unroll 2
    for (int k = 0; k < NH; ++k) {
      float wr = W1[(2 * NH + k) * 256 + t];  // ref_h rows of W1
      a0 += W_emb[k] * wr;
      a1 += W_emb[NH + k] * wr;
      a2 += b_emb[k] * wr + zb[k] * W1[(NH + k) * 256 + t];
    }
    sm.red[t] = a0;
    sm.red[256 + t] = a1;
    sm.red[512 + t] = a2 + b1[t];
  }
  // S = W1[:H] @ W2  (128x128), staged in preA/preP region (filled later)
  {
    float* S = sm.preA;
    for (int k = kqS; k < NH; k += 4) {
      const float* w1row = W1 + k * 256;
      float acc = 0.f;
#pragma unroll 4
      for (int m = 0; m < 256; ++m) acc += w1row[m] * W2[m * NH + oS];
      S[k * NH + oS] = acc;
    }
  }
  __syncthreads();
  // ================= startup phase 1 =================
  // WfT[o][k] = sum_j S[k][j] * Wp[H+j][o]
  {
    const float* S = sm.preA;
    for (int k = kqS; k < NH; k += 4) {
      const float* srow = S + k * NH;
      float acc = 0.f;
#pragma unroll 4
      for (int j = 0; j < NH; ++j) acc += srow[j] * Wp[(NH + j) * NH + oS];
      sm.WfT[oS * PITCH + k] = acc;
    }
  }
  // v[c][j] = am[c] @ W2  (+ b2 for c=2)
  if (t < 384) {
    const int c = t >> 7, j = t & 127;
    const float* amc = sm.red + c * 256;
    float acc = (c == 2) ? b2[j] : 0.f;
#pragma unroll 4
    for (int m = 0; m < 256; ++m) acc += amc[m] * W2[m * NH + j];
    sm.red[768 + t] = acc;
  }
  __syncthreads();
  // ================= startup phase 2 =================
  // U[c][o] = v[c] @ Wp[H:]
  if (t < 384) {
    const int c = t >> 7, o = t & 127;
    const float* vc = sm.red + 768 + c * NH;
    float acc = 0.f;
#pragma unroll 4
    for (int j = 0; j < NH; ++j) acc += vc[j] * Wp[(NH + j) * NH + o];
    sm.U[c * NH + o] = acc;
  }
  // preA / preP (overwrites the S scratch region)
  for (int o = t; o < NS * NH; o += 512) {
    int s = o >> 7, j = o & 127;
    const float* row = ihb + s * NH;
    float a0 = 0.f, a1 = 0.f, p0 = 0.f, p1 = 0.f;
#pragma unroll 4
    for (int k = 0; k < NH; k += 2) {
      float r0 = row[k], r1 = row[k + 1];
      a0 += r0 * W_a[k * NH + j];
      a1 += r1 * W_a[(k + 1) * NH + j];
      p0 += r0 * Wp[k * NH + j];
      p1 += r1 * Wp[(k + 1) * NH + j];
    }
    sm.preA[s * PITCH + j] = a0 + a1;
    sm.preP[s * PITCH + j] = p0 + p1;
  }
  __syncthreads();
  if (t == 0) {
    int s0 = sm.sol[0];
    sm.maskv[s0] = 0.0f;
    sm.refin[0] = sm.inst[2 * s0];
    sm.refin[1] = sm.inst[2 * s0 + 1];
    out[b * NS] = (float)s0;
  }

  // ---------- 63 sequential decode steps (10 barriers/step) ----------
  int cur = 0;
  for (int step = 1; step <= NSTEPS; ++step) {
    const int nxt = cur ^ 1;
    __syncthreads();  // (1) H updates / startup visible
    // A: GRU fused -> hbuf[nxt] (reg W_hh, intra-wave quad-shfl)
    {
      float ar = 0.f, az = 0.f, an = 0.f;
      const float* hp = sm.hbuf[cur] + 36 * q4;  // padh(32*q4)
#pragma unroll
      for (int j = 0; j < 8; ++j) {
        float4 hv = *(const float4*)(hp + 4 * j);
        ar += hv.x * whr[j].x + hv.y * whr[j].y + hv.z * whr[j].z + hv.w * whr[j].w;
        az += hv.x * whz[j].x + hv.y * whz[j].y + hv.z * whz[j].z + hv.w * whz[j].w;
        an += hv.x * whn[j].x + hv.y * whn[j].y + hv.z * whn[j].z + hv.w * whn[j].w;
      }
      ar += __shfl_xor(ar, 1); ar += __shfl_xor(ar, 2);
      az += __shfl_xor(az, 1); az += __shfl_xor(az, 2);
      an += __shfl_xor(an, 1); an += __shfl_xor(an, 2);
      if (q4 == 0) {
        float ghr = ar + sm.bhh[o4];
        float ghz = az + sm.bhh[NH + o4];
        float ghn = an + sm.bhh[2 * NH + o4];
        float r0 = sm.refin[0], r1 = sm.refin[1];
        float gir = r0 * sm.Gpre[o4] + r1 * sm.Gpre[384 + o4] + sm.Gpre[768 + o4];
        float giz = r0 * sm.Gpre[NH + o4] + r1 * sm.Gpre[384 + NH + o4] + sm.Gpre[768 + NH + o4];
        float gin = r0 * sm.Gpre[2 * NH + o4] + r1 * sm.Gpre[384 + 2 * NH + o4] + sm.Gpre[768 + 2 * NH + o4];
        // recurrent path keeps libm precision (h feeds back 63 steps)
        float r = 1.f / (1.f + expf(-(gir + ghr)));
        float z = 1.f / (1.f + expf(-(giz + ghz)));
        float n = tanhf(gin + r * ghn);
        sm.hbuf[nxt][padh(o4)] = (1.f - z) * n + z * sm.hbuf[cur][padh(o4)];
      }
    }
    __syncthreads();  // (2)
    // B: atth partials = h @ W_a[H:] (streamed row-major; 64 KB/step, L2-resident)
    {
      float4 acc = {0.f, 0.f, 0.f, 0.f};
      const float* wap = W_a + (NH + 8 * qB) * NH + ob;
      const float* hp = sm.hbuf[nxt] + padh(8 * qB);
      float4 h0 = *(const float4*)(hp);
      float4 h1 = *(const float4*)(hp + 4);
      float hk[8] = {h0.x, h0.y, h0.z, h0.w, h1.x, h1.y, h1.z, h1.w};
#pragma unroll
      for (int kk = 0; kk < 8; ++kk) {
        float4 w = *(const float4*)(wap + kk * NH);
        acc.x += hk[kk] * w.x; acc.y += hk[kk] * w.y;
        acc.z += hk[kk] * w.z; acc.w += hk[kk] * w.w;
      }
      *(float4*)(sm.red + qB * NH + ob) = acc;
    }
    __syncthreads();  // (3)
    if (t < NH) {  // Bsum
      float s = 0.f;
#pragma unroll
      for (int q = 0; q < 16; ++q) s += sm.red[q * NH + t];
      sm.atth[padh(t)] = s;
    }
    __syncthreads();  // (4)
    // C: attention tanh-dot, octet-shfl reduce -> red[s]
    {
      const float* pa = sm.preA + s8 * PITCH + 16 * q8;
      const float* ah = sm.atth + po8;
      const float* vv = sm.va + po8;
      float acc = 0.f;
#pragma unroll
      for (int u = 0; u < 4; ++u) {
        float4 a = *(const float4*)(pa + 4 * u);
        float4 hh = *(const float4*)(ah + 4 * u);
        float4 vw = *(const float4*)(vv + 4 * u);
        acc += ftanh(a.x + hh.x) * vw.x + ftanh(a.y + hh.y) * vw.y +
               ftanh(a.z + hh.z) * vw.z + ftanh(a.w + hh.w) * vw.w;
      }
      acc += __shfl_xor(acc, 1); acc += __shfl_xor(acc, 2); acc += __shfl_xor(acc, 4);
      if (q8 == 0) sm.red[s8] = acc;
    }
    __syncthreads();  // (5)
    // softmax over s (wave 0)
    if (t < NS) {
      float e = sm.red[t];
      float m = e;
#pragma unroll
      for (int off = 32; off > 0; off >>= 1) m = fmaxf(m, __shfl_xor(m, off));
      float p = __expf(e - m);
      float ssum = p;
#pragma unroll
      for (int off = 32; off > 0; off >>= 1) ssum += __shfl_xor(ssum, off);
      sm.attn[t] = p / ssum;
    }
    __syncthreads();  // (6)
    // D: context partials (IH streamed; 32 KB/step, L2-resident)
    {
      float4 acc = {0.f, 0.f, 0.f, 0.f};
      const float* ib = ihb + (4 * qB) * NH + ob;
      float4 av = *(const float4*)(sm.attn + 4 * qB);
      float as[4] = {av.x, av.y, av.z, av.w};
#pragma unroll
      for (int ss = 0; ss < 4; ++ss) {
        float4 x = *(const float4*)(ib + ss * NH);
        acc.x += as[ss] * x.x; acc.y += as[ss] * x.y;
        acc.z += as[ss] * x.z; acc.w += as[ss] * x.w;
      }
      *(float4*)(sm.red + qB * NH + ob) = acc;
    }
    __syncthreads();  // (7)
    if (t < NH) {  // Dsum
      float s = 0.f;
#pragma unroll
      for (int q = 0; q < 16; ++q) s += sm.red[q * NH + t];
      sm.ctx[padh(t)] = s;
    }
    __syncthreads();  // (8)
    // P: ptrh = ctx @ WfoldT + refin-affine  (LDS single-phase; replaces E1/E2/F)
    {
      float acc = 0.f;
      const float* cp = sm.ctx + 36 * q4;  // padh(32*q4)
      const float* wf = sm.WfT + o4 * PITCH + 32 * q4;
#pragma unroll
      for (int j = 0; j < 8; ++j) {
        float4 cv = *(const float4*)(cp + 4 * j);
        float4 wv = *(const float4*)(wf + 4 * j);
        acc += cv.x * wv.x + cv.y * wv.y + cv.z * wv.z + cv.w * wv.w;
      }
      acc += __shfl_xor(acc, 1); acc += __shfl_xor(acc, 2);
      if (q4 == 0) {
        float r0 = sm.refin[0], r1 = sm.refin[1];
        sm.ptrh[padh(o4)] = acc + r0 * sm.U[o4] + r1 * sm.U[NH + o4] + sm.U[2 * NH + o4];
      }
    }
    __syncthreads();  // (9)
    // G: pointer tanh-dot, octet-shfl reduce -> red[s]
    {
      const float* pp = sm.preP + s8 * PITCH + 16 * q8;
      const float* ph = sm.ptrh + po8;
      const float* vv = sm.vpv + po8;
      float acc = 0.f;
#pragma unroll
      for (int u = 0; u < 4; ++u) {
        float4 a = *(const float4*)(pp + 4 * u);
        float4 hh = *(const float4*)(ph + 4 * u);
        float4 vw = *(const float4*)(vv + 4 * u);
        acc += ftanh(a.x + hh.x) * vw.x + ftanh(a.y + hh.y) * vw.y +
               ftanh(a.z + hh.z) * vw.z + ftanh(a.w + hh.w) * vw.w;
      }
      acc += __shfl_xor(acc, 1); acc += __shfl_xor(acc, 2); acc += __shfl_xor(acc, 4);
      if (q8 == 0) sm.red[s8] = acc;
    }
    __syncthreads();  // (10)
    // H: masked log-softmax, argmax (first-index tie), outputs, state update
    if (t < NS) {
      float lg = sm.red[t];
      float ml = (sm.maskv[t] > 0.5f) ? lg : -INFINITY;
      float m = ml;
      int mi = t;
#pragma unroll
      for (int off = 32; off > 0; off >>= 1) {
        float om = __shfl_xor(m, off);
        int oi = __shfl_xor(mi, off);
        if (om > m || (om == m && oi < mi)) { m = om; mi = oi; }
      }
      float p = __expf(ml - m);
      float ssum = p;
#pragma unroll
      for (int off = 32; off > 0; off >>= 1) ssum += __shfl_xor(ssum, off);
      int ptr = sm.sol[step];
      float pv = __shfl(ml, ptr);
      if (t == 0) {
        out[b * NS + step] = (float)mi;
        out[NB * NS + b * NSTEPS + (step - 1)] = pv - m - __logf(ssum);
        sm.maskv[ptr] = 0.0f;
        sm.refin[0] = sm.inst[2 * ptr];
        sm.refin[1] = sm.inst[2 * ptr + 1];
      }
    }
    cur = nxt;
  }
}

extern "C" void kernel_launch(void* const* d_in, const int* in_sizes, int n_in,
                              void* d_out, int out_size, void* d_ws,
                              size_t ws_size, hipStream_t stream) {
  (void)in_sizes; (void)n_in; (void)out_size; (void)d_ws; (void)ws_size;
  const float* instance = (const float*)d_in[0];
  const int*   solution = (const int*)d_in[1];
  const float* Z        = (const float*)d_in[2];
  const float* IH       = (const float*)d_in[3];
  const float* last_hh  = (const float*)d_in[4];
  const float* W_emb    = (const float*)d_in[5];
  const float* b_emb    = (const float*)d_in[6];
  const float* W_ih     = (const float*)d_in[7];
  const float* W_hh     = (const float*)d_in[8];
  const float* b_ih     = (const float*)d_in[9];
  const float* b_hh     = (const float*)d_in[10];
  const float* W_a      = (const float*)d_in[11];
  const float* v_a      = (const float*)d_in[12];
  const float* W1       = (const float*)d_in[13];
  const float* b1       = (const float*)d_in[14];
  const float* W2       = (const float*)d_in[15];
  const float* b2       = (const float*)d_in[16];
  const float* Wp       = (const float*)d_in[17];
  const float* vp       = (const float*)d_in[18];
  float* out = (float*)d_out;

  const int shmem = (int)sizeof(SM);
  static_assert(sizeof(SM) <= 160 * 1024, "LDS overlay too big");
  hipFuncSetAttribute((const void*)decoder_kernel,
                      hipFuncAttributeMaxDynamicSharedMemorySize, shmem);
  decoder_kernel<<<NB, 512, shmem, stream>>>(
      instance, solution, Z, IH, last_hh, W_emb, b_emb, W_ih, W_hh, b_ih, b_hh,
      W_a, v_a, W1, b1, W2, b2, Wp, vp, out);
}

// Round 6
// 832.550 us; speedup vs baseline: 2.8971x; 1.1559x over previous
//
#include <hip/hip_runtime.h>
#include <math.h>

#define NB 256
#define NS 64
#define NH 128
#define NZ 128
#define NSTEPS 63
#define HP 144   // Hall row pitch (padh layout within each row)
#define PP 132   // preA/preP/atthB(ptrh)/ctx row pitch
#define SP 68    // scores row pitch (mult of 4 for b128 alignment)

// float-offsets into dynamic LDS (total 39808 floats = 159232 B < 160 KiB)
#define OFF_HALL 0                  // 64*144 = 9216  (h_j rows, padded layout)
#define OFF_PREA 9216               // 8448; ctx_all after C; S-scratch spans PREA..PREA+16384
#define OFF_PREP 17664              // 8448
#define OFF_ATTH 26112              // 8448; ptrh_all after C
#define OFF_SCOR 34560              // 64*68 = 4352; pre-C holds Gpre/bhh/am/v
#define OFF_GPRE (OFF_SCOR)         // 1152 (dead after h-chain)
#define OFF_BHH  (OFF_SCOR + 1152)  // 384  (dead after h-chain)
#define OFF_AM   (OFF_SCOR + 1536)  // 768  (startup scratch)
#define OFF_V    (OFF_SCOR + 2304)  // 384  (startup scratch)
#define OFF_U    38912              // 384
#define OFF_VA   39296              // 128
#define OFF_VPV  39424              // 128
#define OFF_REFX 39552              // 64
#define OFF_REFY 39616              // 64
#define OFF_SOL  39680              // 64 (int)
#define OFF_RANK 39744              // 64 (int)
#define SM_FLOATS 39808

// +4 pad per 32-float chunk (identity within chunks; r1-validated conflict fix)
__device__ __forceinline__ int padh(int i) { return i + ((i >> 5) << 2); }

// fast tanh for the non-recurrent score paths (validated r1/r4/r5)
__device__ __forceinline__ float ftanh(float x) {
  float e = __expf(2.0f * x);
  return 1.0f - 2.0f * __builtin_amdgcn_rcpf(e + 1.0f);
}

// Teacher forcing => refin/mask are solution-driven: the ONLY cross-step serial
// dependency is the GRU h-chain. Phase plan: startup -> 63-iter h-chain ->
// 7 batched phases over all 63 steps at once (GEMM-shaped, no per-step barriers).
__global__ __launch_bounds__(512, 2) void decoder_kernel(
    const float* __restrict__ instance, const int* __restrict__ solution,
    const float* __restrict__ Z, const float* __restrict__ IH,
    const float* __restrict__ last_hh, const float* __restrict__ W_emb,
    const float* __restrict__ b_emb, const float* __restrict__ W_ih,
    const float* __restrict__ W_hh, const float* __restrict__ b_ih,
    const float* __restrict__ b_hh, const float* __restrict__ W_a,
    const float* __restrict__ v_a, const float* __restrict__ W1,
    const float* __restrict__ b1, const float* __restrict__ W2,
    const float* __restrict__ b2, const float* __restrict__ Wp,
    const float* __restrict__ vp, float* __restrict__ gWf,
    float* __restrict__ out) {
  extern __shared__ float sm[];
  int* soli = (int*)(sm + OFF_SOL);
  int* ranki = (int*)(sm + OFF_RANK);
  const int b = blockIdx.x;
  const int t = threadIdx.x;
  const float* ihb = IH + b * NS * NH;

  // ---------- thread-role constants ----------
  const int o4 = t >> 2, q4 = t & 3;        // h-chain: 128 outs x 4 k-chunks
  const int oq = (t & 31) * 4, jg = t >> 5; // GEMM phases: o-quad x 16 j-strips
  const int jj = t >> 3, sq = t & 7;        // score phases: 64 j x 8 s-chunks
  const int oS = t & 127, kq = t >> 7;      // startup GEMMs: 128 cols x 4 k-groups

  // ---------- persistent register W_hh cache (96 VGPRs; r0/r4/r5-proven) ----------
  float4 whr[8], whz[8], whn[8];
  {
    const float* br = W_hh + (0 * NH + o4) * NH + 32 * q4;
    const float* bz = W_hh + (1 * NH + o4) * NH + 32 * q4;
    const float* bn = W_hh + (2 * NH + o4) * NH + 32 * q4;
#pragma unroll
    for (int j = 0; j < 8; ++j) {
      whr[j] = *(const float4*)(br + 4 * j);
      whz[j] = *(const float4*)(bz + 4 * j);
      whn[j] = *(const float4*)(bn + 4 * j);
    }
  }

  // ================= startup phase 0 =================
  if (t < NS) {
    int sv = solution[b * NS + t];
    soli[t] = sv;
    ranki[sv] = t;  // rank of node sv in the tour
    sm[OFF_REFX + t] = instance[(b * NS + sv) * 2 + 0];
    sm[OFF_REFY + t] = instance[(b * NS + sv) * 2 + 1];
  }
  if (t < NH) {
    sm[OFF_HALL + padh(t)] = last_hh[b * NH + t];  // h0 row
    sm[OFF_VA + t] = v_a[t];
    sm[OFF_VPV + t] = vp[t];
  }
  if (t < 384) sm[OFF_BHH + t] = b_hh[t];
  // Gpre[c][o3] = [W_emb;b_emb][c] . W_ih[o3,:]  (+ b_ih for c=2)
  if (t < 384) {
    const float* wi = W_ih + t * NH;
    float g0 = 0.f, g1 = 0.f, g2 = 0.f;
#pragma unroll 4
    for (int k4 = 0; k4 < 32; ++k4) {
      float4 w = *(const float4*)(wi + 4 * k4);
      float4 e0 = *(const float4*)(W_emb + 4 * k4);
      float4 e1 = *(const float4*)(W_emb + NH + 4 * k4);
      float4 eb = *(const float4*)(b_emb + 4 * k4);
      g0 += w.x * e0.x + w.y * e0.y + w.z * e0.z + w.w * e0.w;
      g1 += w.x * e1.x + w.y * e1.y + w.z * e1.z + w.w * e1.w;
      g2 += w.x * eb.x + w.y * eb.y + w.z * eb.z + w.w * eb.w;
    }
    sm[OFF_GPRE + t] = g0;
    sm[OFF_GPRE + 384 + t] = g1;
    sm[OFF_GPRE + 768 + t] = g2 + b_ih[t];
  }
  // am[c][m]: fc1 affine inputs (ref_h coords + Z/bias fold)
  if (t < 256) {
    const float* zb = Z + b * NZ;
    float a0 = 0.f, a1 = 0.f, a2 = 0.f;
#pragma unroll 2
    for (int k = 0; k < NH; ++k) {
      float wr = W1[(2 * NH + k) * 256 + t];
      a0 += W_emb[k] * wr;
      a1 += W_emb[NH + k] * wr;
      a2 += b_emb[k] * wr + zb[k] * W1[(NH + k) * 256 + t];
    }
    sm[OFF_AM + t] = a0;
    sm[OFF_AM + 256 + t] = a1;
    sm[OFF_AM + 512 + t] = a2 + b1[t];
  }
  // S = W1[:H] @ W2 (128x128) staged in PREA..PREA+16384 (spans preA+preP)
  for (int k = kq; k < NH; k += 4) {
    const float* w1row = W1 + k * 256;
    float acc = 0.f;
#pragma unroll 4
    for (int m = 0; m < 256; ++m) acc += w1row[m] * W2[m * NH + oS];
    sm[OFF_PREA + k * NH + oS] = acc;
  }
  __syncthreads();
  // ================= startup phase 1 =================
  // Wf[k][o] = S[k] . Wp[H:][:,o]  -> GLOBAL scratch (identical across blocks;
  // racing identical-value writes are benign; block reads only what it wrote)
  for (int k = kq; k < NH; k += 4) {
    const float* srow = sm + OFF_PREA + k * NH;
    float acc = 0.f;
#pragma unroll 4
    for (int j = 0; j < NH; ++j) acc += srow[j] * Wp[(NH + j) * NH + oS];
    gWf[k * NH + oS] = acc;
  }
  // v[c] = am[c] @ W2 (+ b2 for c=2)
  if (t < 384) {
    const int c = t >> 7, jc = t & 127;
    const float* amc = sm + OFF_AM + c * 256;
    float acc = (c == 2) ? b2[jc] : 0.f;
#pragma unroll 4
    for (int m = 0; m < 256; ++m) acc += amc[m] * W2[m * NH + jc];
    sm[OFF_V + t] = acc;
  }
  __syncthreads();
  // ================= startup phase 2 =================
  if (t < 384) {  // U[c] = v[c] @ Wp[H:]
    const int c = t >> 7, o = t & 127;
    const float* vc = sm + OFF_V + c * NH;
    float acc = 0.f;
#pragma unroll 4
    for (int j = 0; j < NH; ++j) acc += vc[j] * Wp[(NH + j) * NH + o];
    sm[OFF_U + t] = acc;
  }
  // preA / preP (overwrites S scratch)
  for (int o = t; o < NS * NH; o += 512) {
    int s = o >> 7, jx = o & 127;
    const float* row = ihb + s * NH;
    float a0 = 0.f, a1 = 0.f, p0 = 0.f, p1 = 0.f;
#pragma unroll 4
    for (int k = 0; k < NH; k += 2) {
      float r0 = row[k], r1 = row[k + 1];
      a0 += r0 * W_a[k * NH + jx];
      a1 += r1 * W_a[(k + 1) * NH + jx];
      p0 += r0 * Wp[k * NH + jx];
      p1 += r1 * Wp[(k + 1) * NH + jx];
    }
    sm[OFF_PREA + s * PP + jx] = a0 + a1;
    sm[OFF_PREP + s * PP + jx] = p0 + p1;
  }
  if (t == 0) out[b * NS] = (float)soli[0];
  __syncthreads();

  // ========== h-chain: the ONLY serial recurrence (63 iters, 1 barrier each) ==========
#pragma unroll 1
  for (int j = 1; j <= NSTEPS; ++j) {
    float ar = 0.f, az = 0.f, an = 0.f;
    const float* hp = sm + OFF_HALL + (j - 1) * HP + 36 * q4;  // padh(32*q4)
#pragma unroll
    for (int u = 0; u < 8; ++u) {
      float4 hv = *(const float4*)(hp + 4 * u);
      ar += hv.x * whr[u].x + hv.y * whr[u].y + hv.z * whr[u].z + hv.w * whr[u].w;
      az += hv.x * whz[u].x + hv.y * whz[u].y + hv.z * whz[u].z + hv.w * whz[u].w;
      an += hv.x * whn[u].x + hv.y * whn[u].y + hv.z * whn[u].z + hv.w * whn[u].w;
    }
    ar += __shfl_xor(ar, 1); ar += __shfl_xor(ar, 2);
    az += __shfl_xor(az, 1); az += __shfl_xor(az, 2);
    an += __shfl_xor(an, 1); an += __shfl_xor(an, 2);
    if (q4 == 0) {
      float ghr = ar + sm[OFF_BHH + o4];
      float ghz = az + sm[OFF_BHH + NH + o4];
      float ghn = an + sm[OFF_BHH + 2 * NH + o4];
      float r0 = sm[OFF_REFX + (j - 1)], r1 = sm[OFF_REFY + (j - 1)];
      float gir = r0 * sm[OFF_GPRE + o4] + r1 * sm[OFF_GPRE + 384 + o4] + sm[OFF_GPRE + 768 + o4];
      float giz = r0 * sm[OFF_GPRE + NH + o4] + r1 * sm[OFF_GPRE + 384 + NH + o4] + sm[OFF_GPRE + 768 + NH + o4];
      float gin = r0 * sm[OFF_GPRE + 2 * NH + o4] + r1 * sm[OFF_GPRE + 384 + 2 * NH + o4] + sm[OFF_GPRE + 768 + 2 * NH + o4];
      // recurrent path keeps libm precision (compounds over 63 steps)
      float r = 1.f / (1.f + expf(-(gir + ghr)));
      float z = 1.f / (1.f + expf(-(giz + ghz)));
      float n = tanhf(gin + r * ghn);
      float hold = sm[OFF_HALL + (j - 1) * HP + padh(o4)];
      sm[OFF_HALL + j * HP + padh(o4)] = (1.f - z) * n + z * hold;
    }
    __syncthreads();
  }

  // ========== B: atthB[j] = h_j @ W_a[H:]  (batched GEMM, W_a2 streamed L2) ==========
  {
    float4 acc[4];
#pragma unroll
    for (int i = 0; i < 4; ++i) acc[i] = (float4){0.f, 0.f, 0.f, 0.f};
    const float* wbase = W_a + NH * NH + oq;
#pragma unroll 4
    for (int k4 = 0; k4 < 32; ++k4) {
      int k = 4 * k4;
      int hoff = k + 4 * (k4 >> 3);  // padh offset (contiguous within 32-chunk)
      float4 w0 = *(const float4*)(wbase + (k + 0) * NH);
      float4 w1 = *(const float4*)(wbase + (k + 1) * NH);
      float4 w2 = *(const float4*)(wbase + (k + 2) * NH);
      float4 w3 = *(const float4*)(wbase + (k + 3) * NH);
#pragma unroll
      for (int i = 0; i < 4; ++i) {
        float4 hv = *(const float4*)(sm + OFF_HALL + (jg + 16 * i) * HP + hoff);
        acc[i].x += hv.x * w0.x + hv.y * w1.x + hv.z * w2.x + hv.w * w3.x;
        acc[i].y += hv.x * w0.y + hv.y * w1.y + hv.z * w2.y + hv.w * w3.y;
        acc[i].z += hv.x * w0.z + hv.y * w1.z + hv.z * w2.z + hv.w * w3.z;
        acc[i].w += hv.x * w0.w + hv.y * w1.w + hv.z * w2.w + hv.w * w3.w;
      }
    }
#pragma unroll
    for (int i = 0; i < 4; ++i)
      *(float4*)(sm + OFF_ATTH + (jg + 16 * i) * PP + oq) = acc[i];
  }
  __syncthreads();

  // ========== C: scores[j][s] = sum_o ftanh(preA[s][o]+atthB[j][o])*va[o] ==========
  {
    const float* ah = sm + OFF_ATTH + jj * PP;
    for (int i = 0; i < 8; ++i) {
      int s = sq + 8 * i;  // stride-8 s => preA rows hit disjoint bank quads
      const float* pa = sm + OFF_PREA + s * PP;
      float acc = 0.f;
#pragma unroll 8
      for (int k4 = 0; k4 < 32; ++k4) {
        float4 a = *(const float4*)(pa + 4 * k4);
        float4 h = *(const float4*)(ah + 4 * k4);
        float4 v = *(const float4*)(sm + OFF_VA + 4 * k4);
        acc += ftanh(a.x + h.x) * v.x + ftanh(a.y + h.y) * v.y +
               ftanh(a.z + h.z) * v.z + ftanh(a.w + h.w) * v.w;
      }
      sm[OFF_SCOR + jj * SP + s] = acc;
    }
  }
  __syncthreads();

  // ========== softmax over s (per j; 8-lane groups, in place) ==========
  {
    const float* sr = sm + OFF_SCOR + jj * SP + 8 * sq;
    float4 ea = *(const float4*)(sr);
    float4 eb = *(const float4*)(sr + 4);
    float e0 = ea.x, e1 = ea.y, e2 = ea.z, e3 = ea.w;
    float e4 = eb.x, e5 = eb.y, e6 = eb.z, e7 = eb.w;
    float m = fmaxf(fmaxf(fmaxf(e0, e1), fmaxf(e2, e3)),
                    fmaxf(fmaxf(e4, e5), fmaxf(e6, e7)));
    m = fmaxf(m, __shfl_xor(m, 1));
    m = fmaxf(m, __shfl_xor(m, 2));
    m = fmaxf(m, __shfl_xor(m, 4));
    float p0 = __expf(e0 - m), p1 = __expf(e1 - m), p2 = __expf(e2 - m), p3 = __expf(e3 - m);
    float p4 = __expf(e4 - m), p5 = __expf(e5 - m), p6 = __expf(e6 - m), p7 = __expf(e7 - m);
    float ssum = ((p0 + p1) + (p2 + p3)) + ((p4 + p5) + (p6 + p7));
    ssum += __shfl_xor(ssum, 1); ssum += __shfl_xor(ssum, 2); ssum += __shfl_xor(ssum, 4);
    float4 oa, ob2;
    oa.x = p0 / ssum; oa.y = p1 / ssum; oa.z = p2 / ssum; oa.w = p3 / ssum;
    ob2.x = p4 / ssum; ob2.y = p5 / ssum; ob2.z = p6 / ssum; ob2.w = p7 / ssum;
    *(float4*)(sm + OFF_SCOR + jj * SP + 8 * sq) = oa;
    *(float4*)(sm + OFF_SCOR + jj * SP + 8 * sq + 4) = ob2;
  }
  __syncthreads();

  // ========== D: ctx[j] = attn[j] @ IH  (into preA buffer; IH streamed L2) ==========
  {
    float4 acc[4];
#pragma unroll
    for (int i = 0; i < 4; ++i) acc[i] = (float4){0.f, 0.f, 0.f, 0.f};
    const float* ibase = ihb + oq;
#pragma unroll 4
    for (int s4 = 0; s4 < 16; ++s4) {
      int s = 4 * s4;
      float4 x0 = *(const float4*)(ibase + (s + 0) * NH);
      float4 x1 = *(const float4*)(ibase + (s + 1) * NH);
      float4 x2 = *(const float4*)(ibase + (s + 2) * NH);
      float4 x3 = *(const float4*)(ibase + (s + 3) * NH);
#pragma unroll
      for (int i = 0; i < 4; ++i) {
        const float* at = sm + OFF_SCOR + (jg + 16 * i) * SP + s;
        float a0 = at[0], a1 = at[1], a2 = at[2], a3 = at[3];
        acc[i].x += a0 * x0.x + a1 * x1.x + a2 * x2.x + a3 * x3.x;
        acc[i].y += a0 * x0.y + a1 * x1.y + a2 * x2.y + a3 * x3.y;
        acc[i].z += a0 * x0.z + a1 * x1.z + a2 * x2.z + a3 * x3.z;
        acc[i].w += a0 * x0.w + a1 * x1.w + a2 * x2.w + a3 * x3.w;
      }
    }
#pragma unroll
    for (int i = 0; i < 4; ++i)
      *(float4*)(sm + OFF_PREA + (jg + 16 * i) * PP + oq) = acc[i];
  }
  __syncthreads();

  // ========== P: ptrh[j] = ctx[j] @ Wf + r0*U0 + r1*U1 + U2  (into atthB buf) ==========
  {
    float4 acc[4];
#pragma unroll
    for (int i = 0; i < 4; ++i) acc[i] = (float4){0.f, 0.f, 0.f, 0.f};
    const float* wfb = gWf + oq;
#pragma unroll 4
    for (int k4 = 0; k4 < 32; ++k4) {
      int k = 4 * k4;
      float4 w0 = *(const float4*)(wfb + (k + 0) * NH);
      float4 w1 = *(const float4*)(wfb + (k + 1) * NH);
      float4 w2 = *(const float4*)(wfb + (k + 2) * NH);
      float4 w3 = *(const float4*)(wfb + (k + 3) * NH);
#pragma unroll
      for (int i = 0; i < 4; ++i) {
        float4 cv = *(const float4*)(sm + OFF_PREA + (jg + 16 * i) * PP + k);
        acc[i].x += cv.x * w0.x + cv.y * w1.x + cv.z * w2.x + cv.w * w3.x;
        acc[i].y += cv.x * w0.y + cv.y * w1.y + cv.z * w2.y + cv.w * w3.y;
        acc[i].z += cv.x * w0.z + cv.y * w1.z + cv.z * w2.z + cv.w * w3.z;
        acc[i].w += cv.x * w0.w + cv.y * w1.w + cv.z * w2.w + cv.w * w3.w;
      }
    }
    float4 u0 = *(const float4*)(sm + OFF_U + oq);
    float4 u1 = *(const float4*)(sm + OFF_U + NH + oq);
    float4 u2 = *(const float4*)(sm + OFF_U + 2 * NH + oq);
#pragma unroll
    for (int i = 0; i < 4; ++i) {
      int j = jg + 16 * i;
      int jm = (j > 0) ? (j - 1) : 0;  // row 0 unused; clamp avoids OOB
      float rx = sm[OFF_REFX + jm], ry = sm[OFF_REFY + jm];
      float4 r;
      r.x = acc[i].x + rx * u0.x + ry * u1.x + u2.x;
      r.y = acc[i].y + rx * u0.y + ry * u1.y + u2.y;
      r.z = acc[i].z + rx * u0.z + ry * u1.z + u2.z;
      r.w = acc[i].w + rx * u0.w + ry * u1.w + u2.w;
      *(float4*)(sm + OFF_ATTH + j * PP + oq) = r;
    }
  }
  __syncthreads();

  // ========== G: glogits[j][s] = sum_o ftanh(preP[s][o]+ptrh[j][o])*vp[o] ==========
  {
    const float* ph = sm + OFF_ATTH + jj * PP;
    for (int i = 0; i < 8; ++i) {
      int s = sq + 8 * i;
      const float* pp = sm + OFF_PREP + s * PP;
      float acc = 0.f;
#pragma unroll 8
      for (int k4 = 0; k4 < 32; ++k4) {
        float4 a = *(const float4*)(pp + 4 * k4);
        float4 h = *(const float4*)(ph + 4 * k4);
        float4 v = *(const float4*)(sm + OFF_VPV + 4 * k4);
        acc += ftanh(a.x + h.x) * v.x + ftanh(a.y + h.y) * v.y +
               ftanh(a.z + h.z) * v.z + ftanh(a.w + h.w) * v.w;
      }
      sm[OFF_SCOR + jj * SP + s] = acc;
    }
  }
  __syncthreads();

  // ========== H: masked log-softmax + argmax (first-index tie) + outputs ==========
  {
    const float* lr = sm + OFF_SCOR + jj * SP + 8 * sq;
    float4 la = *(const float4*)(lr);
    float4 lb = *(const float4*)(lr + 4);
    float lg[8] = {la.x, la.y, la.z, la.w, lb.x, lb.y, lb.z, lb.w};
    float ml[8];
    float m = -INFINITY;
    int mi = 127;
#pragma unroll
    for (int i = 0; i < 8; ++i) {
      int s = 8 * sq + i;
      ml[i] = (ranki[s] >= jj) ? lg[i] : -INFINITY;  // mask excludes sol[0..j-1]
      if (ml[i] > m) { m = ml[i]; mi = s; }
    }
#pragma unroll
    for (int off = 1; off <= 4; off <<= 1) {
      float om = __shfl_xor(m, off);
      int oi = __shfl_xor(mi, off);
      if (om > m || (om == m && oi < mi)) { m = om; mi = oi; }
    }
    float ssum = 0.f;
#pragma unroll
    for (int i = 0; i < 8; ++i) ssum += __expf(ml[i] - m);
    ssum += __shfl_xor(ssum, 1); ssum += __shfl_xor(ssum, 2); ssum += __shfl_xor(ssum, 4);
    if (sq == 0 && jj >= 1) {
      out[b * NS + jj] = (float)mi;
      float pv = sm[OFF_SCOR + jj * SP + soli[jj]];  // sol[j] always unmasked at step j
      out[NB * NS + b * NSTEPS + (jj - 1)] = pv - m - __logf(ssum);
    }
  }
}

extern "C" void kernel_launch(void* const* d_in, const int* in_sizes, int n_in,
                              void* d_out, int out_size, void* d_ws,
                              size_t ws_size, hipStream_t stream) {
  (void)in_sizes; (void)n_in; (void)out_size; (void)ws_size;
  const float* instance = (const float*)d_in[0];
  const int*   solution = (const int*)d_in[1];
  const float* Z        = (const float*)d_in[2];
  const float* IH       = (const float*)d_in[3];
  const float* last_hh  = (const float*)d_in[4];
  const float* W_emb    = (const float*)d_in[5];
  const float* b_emb    = (const float*)d_in[6];
  const float* W_ih     = (const float*)d_in[7];
  const float* W_hh     = (const float*)d_in[8];
  const float* b_ih     = (const float*)d_in[9];
  const float* b_hh     = (const float*)d_in[10];
  const float* W_a      = (const float*)d_in[11];
  const float* v_a      = (const float*)d_in[12];
  const float* W1       = (const float*)d_in[13];
  const float* b1       = (const float*)d_in[14];
  const float* W2       = (const float*)d_in[15];
  const float* b2       = (const float*)d_in[16];
  const float* Wp       = (const float*)d_in[17];
  const float* vp       = (const float*)d_in[18];
  float* out = (float*)d_out;
  float* gWf = (float*)d_ws;  // 64 KB scratch for folded MLP weight (G9: use d_ws)

  const int shmem = SM_FLOATS * 4;
  static_assert(SM_FLOATS * 4 <= 160 * 1024, "LDS overlay too big");
  hipFuncSetAttribute((const void*)decoder_kernel,
                      hipFuncAttributeMaxDynamicSharedMemorySize, shmem);
  decoder_kernel<<<NB, 512, shmem, stream>>>(
      instance, solution, Z, IH, last_hh, W_emb, b_emb, W_ih, W_hh, b_ih, b_hh,
      W_a, v_a, W1, b1, W2, b2, Wp, vp, gWf, out);
}

// Round 7
// 475.707 us; speedup vs baseline: 5.0704x; 1.7501x over previous
//
#include <hip/hip_runtime.h>
#include <math.h>

#define NB 256
#define NS 64
#define NH 128
#define NZ 128
#define NSTEPS 63
#define HP 144   // HALL row pitch (padh layout within each row)
#define PP 132   // preA/preP/atth(ptrh)/ctx row pitch
#define SP 68    // scores row pitch

// LDS float-offsets (total 39808 floats = 155.5 KiB)
#define OFF_PREA 0       // 8448
#define OFF_PREP 8448    // 8448 -> [0,16896)
#define OFF_HALL 16896   // 9216 -> [16896,26112)
#define OFF_ATTH 26112   // 8448 -> [26112,34560)
#define OFF_SCOR 34560   // 4352 -> [34560,38912)
#define OFF_U    38912   // 384
#define OFF_VA   39296   // 128
#define OFF_VPV  39424   // 128
#define OFF_REFX 39552   // 64
#define OFF_REFY 39616   // 64
#define OFF_SOL  39680   // 64 (int)
#define OFF_RANK 39744   // 64 (int)
#define SM_FLOATS 39808
// startup temps (regions free until their persistent users start):
#define OFF_S    16896   // S 16384 -> [16896,33280): HALL+ATTH, dead after Wf
#define OFF_IH   16896   // IH_lds 8192 -> [16896,25088): after S dead, before h0
#define OFF_GPRE 34560   // 1152 (SCOR region; SCOR first written after h-chain)
#define OFF_BHH  35712   // 384
#define OFF_AM   36096   // 768  (startup only)
#define OFF_V2   36864   // 384  (startup only)

// +4 pad per 32-float chunk (r1-validated conflict fix for HALL rows)
__device__ __forceinline__ int padh(int i) { return i + ((i >> 5) << 2); }

// fast tanh for the non-recurrent score paths (validated r1/r4/r5/r6)
__device__ __forceinline__ float ftanh(float x) {
  float e = __expf(2.0f * x);
  return 1.0f - 2.0f * __builtin_amdgcn_rcpf(e + 1.0f);
}

// Teacher forcing => only the GRU h-chain is serial. Structure:
// startup (redundancy-free GEMMs) -> 63-iter h-chain -> 7 batched phases.
__global__ __launch_bounds__(512, 2) void decoder_kernel(
    const float* __restrict__ instance, const int* __restrict__ solution,
    const float* __restrict__ Z, const float* __restrict__ IH,
    const float* __restrict__ last_hh, const float* __restrict__ W_emb,
    const float* __restrict__ b_emb, const float* __restrict__ W_ih,
    const float* __restrict__ W_hh, const float* __restrict__ b_ih,
    const float* __restrict__ b_hh, const float* __restrict__ W_a,
    const float* __restrict__ v_a, const float* __restrict__ W1,
    const float* __restrict__ b1, const float* __restrict__ W2,
    const float* __restrict__ b2, const float* __restrict__ Wp,
    const float* __restrict__ vp, float* __restrict__ gWf,
    float* __restrict__ out) {
  extern __shared__ float sm[];
  int* soli = (int*)(sm + OFF_SOL);
  int* ranki = (int*)(sm + OFF_RANK);
  const int b = blockIdx.x;
  const int t = threadIdx.x;
  const float* ihb = IH + b * NS * NH;

  // ---------- thread-role constants ----------
  const int o4 = t >> 2, q4 = t & 3;        // h-chain: 128 outs x 4 k-chunks
  const int oq = (t & 31) * 4, jg = t >> 5; // GEMM phases B/D/P: o-quad x 16 j-strips
  const int jj = t >> 3, sq = t & 7;        // score phases C/G/softmax/H
  const int oS = t & 127, kq = t >> 7;      // startup GEMMs: 128 cols x 4 k-groups (kq wave-uniform)

  // ================= startup phase 0 =================
  if (t < NS) {
    int sv = solution[b * NS + t];
    soli[t] = sv;
    ranki[sv] = t;
    sm[OFF_REFX + t] = instance[(b * NS + sv) * 2 + 0];
    sm[OFF_REFY + t] = instance[(b * NS + sv) * 2 + 1];
  }
  if (t < NH) {
    sm[OFF_VA + t] = v_a[t];
    sm[OFF_VPV + t] = vp[t];
  }
  if (t < 384) sm[OFF_BHH + t] = b_hh[t];
  // Gpre[c][o3] = [W_emb;b_emb][c] . W_ih[o3,:]  (+ b_ih for c=2)
  if (t < 384) {
    const float* wi = W_ih + t * NH;
    float g0 = 0.f, g1 = 0.f, g2 = 0.f;
#pragma unroll 4
    for (int k4 = 0; k4 < 32; ++k4) {
      float4 w = *(const float4*)(wi + 4 * k4);
      float4 e0 = *(const float4*)(W_emb + 4 * k4);
      float4 e1 = *(const float4*)(W_emb + NH + 4 * k4);
      float4 eb = *(const float4*)(b_emb + 4 * k4);
      g0 += w.x * e0.x + w.y * e0.y + w.z * e0.z + w.w * e0.w;
      g1 += w.x * e1.x + w.y * e1.y + w.z * e1.z + w.w * e1.w;
      g2 += w.x * eb.x + w.y * eb.y + w.z * eb.z + w.w * eb.w;
    }
    sm[OFF_GPRE + t] = g0;
    sm[OFF_GPRE + 384 + t] = g1;
    sm[OFF_GPRE + 768 + t] = g2 + b_ih[t];
  }
  // am[c][m]: fc1 affine inputs (ref_h coords + Z/bias fold)
  if (t < 256) {
    const float* zb = Z + b * NZ;
    float a0 = 0.f, a1 = 0.f, a2 = 0.f;
#pragma unroll 2
    for (int k = 0; k < NH; ++k) {
      float wr = W1[(2 * NH + k) * 256 + t];
      a0 += W_emb[k] * wr;
      a1 += W_emb[NH + k] * wr;
      a2 += b_emb[k] * wr + zb[k] * W1[(NH + k) * 256 + t];
    }
    sm[OFF_AM + t] = a0;
    sm[OFF_AM + 256 + t] = a1;
    sm[OFF_AM + 512 + t] = a2 + b1[t];
  }
  // S[k][o] = W1[:H] @ W2, m-outer/acc[8]: W2 read once per 8-k strip (not 32x)
#pragma unroll 1
  for (int p = 0; p < 4; ++p) {
    const int kbase = kq * 32 + 8 * p;
    float acc[8] = {0.f, 0.f, 0.f, 0.f, 0.f, 0.f, 0.f, 0.f};
#pragma unroll 2
    for (int m4 = 0; m4 < 64; ++m4) {
      const int m = 4 * m4;
      float w2a = W2[(m + 0) * NH + oS];
      float w2b = W2[(m + 1) * NH + oS];
      float w2c = W2[(m + 2) * NH + oS];
      float w2d = W2[(m + 3) * NH + oS];
#pragma unroll
      for (int u = 0; u < 8; ++u) {
        float4 w1 = *(const float4*)(W1 + (kbase + u) * 256 + m);
        acc[u] += w1.x * w2a + w1.y * w2b + w1.z * w2c + w1.w * w2d;
      }
    }
#pragma unroll
    for (int u = 0; u < 8; ++u) sm[OFF_S + (kbase + u) * NH + oS] = acc[u];
  }
  __syncthreads();
  // ================= startup phase 1 =================
  // Wf[k][o] = S(LDS) @ Wp[H:], j-outer/acc[8]: Wp2 read once per 8-k strip
#pragma unroll 1
  for (int p = 0; p < 4; ++p) {
    const int kbase = kq * 32 + 8 * p;
    float acc[8] = {0.f, 0.f, 0.f, 0.f, 0.f, 0.f, 0.f, 0.f};
#pragma unroll 2
    for (int j4 = 0; j4 < 32; ++j4) {
      const int j = 4 * j4;
      float wpa = Wp[(NH + j + 0) * NH + oS];
      float wpb = Wp[(NH + j + 1) * NH + oS];
      float wpc = Wp[(NH + j + 2) * NH + oS];
      float wpd = Wp[(NH + j + 3) * NH + oS];
#pragma unroll
      for (int u = 0; u < 8; ++u) {
        float4 s4 = *(const float4*)(sm + OFF_S + (kbase + u) * NH + j);
        acc[u] += s4.x * wpa + s4.y * wpb + s4.z * wpc + s4.w * wpd;
      }
    }
#pragma unroll
    for (int u = 0; u < 8; ++u) gWf[(kbase + u) * NH + oS] = acc[u];
  }
  // v[c] = am[c] @ W2 (+ b2 for c=2)
  if (t < 384) {
    const int c = t >> 7, jc = t & 127;
    const float* amc = sm + OFF_AM + c * 256;
    float acc = (c == 2) ? b2[jc] : 0.f;
#pragma unroll 4
    for (int m = 0; m < 256; ++m) acc += amc[m] * W2[m * NH + jc];
    sm[OFF_V2 + t] = acc;
  }
  __syncthreads();
  // ================= startup phase 2 =================
  if (t < 384) {  // U[c] = v[c] @ Wp[H:]
    const int c = t >> 7, o = t & 127;
    const float* vc = sm + OFF_V2 + c * NH;
    float acc = 0.f;
#pragma unroll 4
    for (int j = 0; j < NH; ++j) acc += vc[j] * Wp[(NH + j) * NH + o];
    sm[OFF_U + c * NH + o] = acc;
  }
  // stage IH tile into LDS (coalesced; S region is dead now)
  for (int i = 4 * t; i < NS * NH; i += 2048)
    *(float4*)(sm + OFF_IH + i) = *(const float4*)(ihb + i);
  __syncthreads();
  // ================= startup phase 3 =================
  // preA/preP: k4-outer/acc[16]x2 — W_a/Wp rows read once (not 16x)
  {
    const int jx = t & 127, sg = t >> 7;  // sg wave-uniform
    float accA[16], accP[16];
#pragma unroll
    for (int si = 0; si < 16; ++si) { accA[si] = 0.f; accP[si] = 0.f; }
#pragma unroll 2
    for (int k4 = 0; k4 < 32; ++k4) {
      const int k = 4 * k4;
      float wa0 = W_a[(k + 0) * NH + jx];
      float wa1 = W_a[(k + 1) * NH + jx];
      float wa2 = W_a[(k + 2) * NH + jx];
      float wa3 = W_a[(k + 3) * NH + jx];
      float wp0 = Wp[(k + 0) * NH + jx];
      float wp1 = Wp[(k + 1) * NH + jx];
      float wp2 = Wp[(k + 2) * NH + jx];
      float wp3 = Wp[(k + 3) * NH + jx];
#pragma unroll
      for (int si = 0; si < 16; ++si) {
        float4 ih = *(const float4*)(sm + OFF_IH + (sg * 16 + si) * NH + k);
        accA[si] += ih.x * wa0 + ih.y * wa1 + ih.z * wa2 + ih.w * wa3;
        accP[si] += ih.x * wp0 + ih.y * wp1 + ih.z * wp2 + ih.w * wp3;
      }
    }
#pragma unroll
    for (int si = 0; si < 16; ++si) {
      sm[OFF_PREA + (sg * 16 + si) * PP + jx] = accA[si];
      sm[OFF_PREP + (sg * 16 + si) * PP + jx] = accP[si];
    }
  }
  if (t == 0) out[b * NS] = (float)soli[0];
  __syncthreads();
  // ================= startup phase 4: h0 (overwrites dead IH region) ========
  if (t < NH) sm[OFF_HALL + padh(t)] = last_hh[b * NH + t];
  __syncthreads();

  // ========== h-chain: the ONLY serial recurrence (63 iters, 1 barrier each).
  // W_hh streamed from L2 each iter (192 KB; compiler refuses to keep 96 VGPRs
  // resident — r1/r3/r6 evidence). Explicit in-loop loads = same traffic.
  {
    const float* br = W_hh + (0 * NH + o4) * NH + 32 * q4;
    const float* bz = W_hh + (1 * NH + o4) * NH + 32 * q4;
    const float* bn = W_hh + (2 * NH + o4) * NH + 32 * q4;
#pragma unroll 1
    for (int j = 1; j <= NSTEPS; ++j) {
      float ar = 0.f, az = 0.f, an = 0.f;
      const float* hp = sm + OFF_HALL + (j - 1) * HP + 36 * q4;  // padh(32*q4)
#pragma unroll
      for (int u = 0; u < 8; ++u) {
        float4 wr = *(const float4*)(br + 4 * u);
        float4 wz = *(const float4*)(bz + 4 * u);
        float4 wn = *(const float4*)(bn + 4 * u);
        float4 hv = *(const float4*)(hp + 4 * u);
        ar += hv.x * wr.x + hv.y * wr.y + hv.z * wr.z + hv.w * wr.w;
        az += hv.x * wz.x + hv.y * wz.y + hv.z * wz.z + hv.w * wz.w;
        an += hv.x * wn.x + hv.y * wn.y + hv.z * wn.z + hv.w * wn.w;
      }
      ar += __shfl_xor(ar, 1); ar += __shfl_xor(ar, 2);
      az += __shfl_xor(az, 1); az += __shfl_xor(az, 2);
      an += __shfl_xor(an, 1); an += __shfl_xor(an, 2);
      if (q4 == 0) {
        float ghr = ar + sm[OFF_BHH + o4];
        float ghz = az + sm[OFF_BHH + NH + o4];
        float ghn = an + sm[OFF_BHH + 2 * NH + o4];
        float r0 = sm[OFF_REFX + (j - 1)], r1 = sm[OFF_REFY + (j - 1)];
        float gir = r0 * sm[OFF_GPRE + o4] + r1 * sm[OFF_GPRE + 384 + o4] + sm[OFF_GPRE + 768 + o4];
        float giz = r0 * sm[OFF_GPRE + NH + o4] + r1 * sm[OFF_GPRE + 384 + NH + o4] + sm[OFF_GPRE + 768 + NH + o4];
        float gin = r0 * sm[OFF_GPRE + 2 * NH + o4] + r1 * sm[OFF_GPRE + 384 + 2 * NH + o4] + sm[OFF_GPRE + 768 + 2 * NH + o4];
        // recurrent path keeps libm precision (compounds over 63 steps)
        float r = 1.f / (1.f + expf(-(gir + ghr)));
        float z = 1.f / (1.f + expf(-(giz + ghz)));
        float n = tanhf(gin + r * ghn);
        float hold = sm[OFF_HALL + (j - 1) * HP + padh(o4)];
        sm[OFF_HALL + j * HP + padh(o4)] = (1.f - z) * n + z * hold;
      }
      __syncthreads();
    }
  }

  // ========== B: atthB[j] = h_j @ W_a[H:] (batched; W_a2 streamed L2) ==========
  {
    float4 acc[4];
#pragma unroll
    for (int i = 0; i < 4; ++i) acc[i] = (float4){0.f, 0.f, 0.f, 0.f};
    const float* wbase = W_a + NH * NH + oq;
#pragma unroll 4
    for (int k4 = 0; k4 < 32; ++k4) {
      int k = 4 * k4;
      int hoff = k + 4 * (k4 >> 3);  // padh offset (contiguous within 32-chunk)
      float4 w0 = *(const float4*)(wbase + (k + 0) * NH);
      float4 w1 = *(const float4*)(wbase + (k + 1) * NH);
      float4 w2 = *(const float4*)(wbase + (k + 2) * NH);
      float4 w3 = *(const float4*)(wbase + (k + 3) * NH);
#pragma unroll
      for (int i = 0; i < 4; ++i) {
        float4 hv = *(const float4*)(sm + OFF_HALL + (jg + 16 * i) * HP + hoff);
        acc[i].x += hv.x * w0.x + hv.y * w1.x + hv.z * w2.x + hv.w * w3.x;
        acc[i].y += hv.x * w0.y + hv.y * w1.y + hv.z * w2.y + hv.w * w3.y;
        acc[i].z += hv.x * w0.z + hv.y * w1.z + hv.z * w2.z + hv.w * w3.z;
        acc[i].w += hv.x * w0.w + hv.y * w1.w + hv.z * w2.w + hv.w * w3.w;
      }
    }
#pragma unroll
    for (int i = 0; i < 4; ++i)
      *(float4*)(sm + OFF_ATTH + (jg + 16 * i) * PP + oq) = acc[i];
  }
  __syncthreads();

  // ========== C: scores[j][s] (k4-outer: atth/va rows read once, not 8x) =====
  {
    const float* ah = sm + OFF_ATTH + jj * PP;
    float accv[8] = {0.f, 0.f, 0.f, 0.f, 0.f, 0.f, 0.f, 0.f};
#pragma unroll 2
    for (int k4 = 0; k4 < 32; ++k4) {
      float4 h = *(const float4*)(ah + 4 * k4);
      float4 v = *(const float4*)(sm + OFF_VA + 4 * k4);
#pragma unroll
      for (int i = 0; i < 8; ++i) {
        float4 a = *(const float4*)(sm + OFF_PREA + (sq + 8 * i) * PP + 4 * k4);
        accv[i] += ftanh(a.x + h.x) * v.x + ftanh(a.y + h.y) * v.y +
                   ftanh(a.z + h.z) * v.z + ftanh(a.w + h.w) * v.w;
      }
    }
#pragma unroll
    for (int i = 0; i < 8; ++i) sm[OFF_SCOR + jj * SP + sq + 8 * i] = accv[i];
  }
  __syncthreads();

  // ========== softmax over s (per j; 8-lane groups, in place) ==========
  {
    const float* sr = sm + OFF_SCOR + jj * SP + 8 * sq;
    float4 ea = *(const float4*)(sr);
    float4 eb = *(const float4*)(sr + 4);
    float e0 = ea.x, e1 = ea.y, e2 = ea.z, e3 = ea.w;
    float e4 = eb.x, e5 = eb.y, e6 = eb.z, e7 = eb.w;
    float m = fmaxf(fmaxf(fmaxf(e0, e1), fmaxf(e2, e3)),
                    fmaxf(fmaxf(e4, e5), fmaxf(e6, e7)));
    m = fmaxf(m, __shfl_xor(m, 1));
    m = fmaxf(m, __shfl_xor(m, 2));
    m = fmaxf(m, __shfl_xor(m, 4));
    float p0 = __expf(e0 - m), p1 = __expf(e1 - m), p2 = __expf(e2 - m), p3 = __expf(e3 - m);
    float p4 = __expf(e4 - m), p5 = __expf(e5 - m), p6 = __expf(e6 - m), p7 = __expf(e7 - m);
    float ssum = ((p0 + p1) + (p2 + p3)) + ((p4 + p5) + (p6 + p7));
    ssum += __shfl_xor(ssum, 1); ssum += __shfl_xor(ssum, 2); ssum += __shfl_xor(ssum, 4);
    float4 oa, ob2;
    oa.x = p0 / ssum; oa.y = p1 / ssum; oa.z = p2 / ssum; oa.w = p3 / ssum;
    ob2.x = p4 / ssum; ob2.y = p5 / ssum; ob2.z = p6 / ssum; ob2.w = p7 / ssum;
    *(float4*)(sm + OFF_SCOR + jj * SP + 8 * sq) = oa;
    *(float4*)(sm + OFF_SCOR + jj * SP + 8 * sq + 4) = ob2;
  }
  __syncthreads();

  // ========== D: ctx[j] = attn[j] @ IH (into preA buffer; IH from L2) ==========
  {
    float4 acc[4];
#pragma unroll
    for (int i = 0; i < 4; ++i) acc[i] = (float4){0.f, 0.f, 0.f, 0.f};
    const float* ibase = ihb + oq;
#pragma unroll 4
    for (int s4 = 0; s4 < 16; ++s4) {
      int s = 4 * s4;
      float4 x0 = *(const float4*)(ibase + (s + 0) * NH);
      float4 x1 = *(const float4*)(ibase + (s + 1) * NH);
      float4 x2 = *(const float4*)(ibase + (s + 2) * NH);
      float4 x3 = *(const float4*)(ibase + (s + 3) * NH);
#pragma unroll
      for (int i = 0; i < 4; ++i) {
        const float* at = sm + OFF_SCOR + (jg + 16 * i) * SP + s;
        float a0 = at[0], a1 = at[1], a2 = at[2], a3 = at[3];
        acc[i].x += a0 * x0.x + a1 * x1.x + a2 * x2.x + a3 * x3.x;
        acc[i].y += a0 * x0.y + a1 * x1.y + a2 * x2.y + a3 * x3.y;
        acc[i].z += a0 * x0.z + a1 * x1.z + a2 * x2.z + a3 * x3.z;
        acc[i].w += a0 * x0.w + a1 * x1.w + a2 * x2.w + a3 * x3.w;
      }
    }
#pragma unroll
    for (int i = 0; i < 4; ++i)
      *(float4*)(sm + OFF_PREA + (jg + 16 * i) * PP + oq) = acc[i];
  }
  __syncthreads();

  // ========== P: ptrh[j] = ctx[j] @ Wf + affine (into atth buffer) ==========
  {
    float4 acc[4];
#pragma unroll
    for (int i = 0; i < 4; ++i) acc[i] = (float4){0.f, 0.f, 0.f, 0.f};
    const float* wfb = gWf + oq;
#pragma unroll 4
    for (int k4 = 0; k4 < 32; ++k4) {
      int k = 4 * k4;
      float4 w0 = *(const float4*)(wfb + (k + 0) * NH);
      float4 w1 = *(const float4*)(wfb + (k + 1) * NH);
      float4 w2 = *(const float4*)(wfb + (k + 2) * NH);
      float4 w3 = *(const float4*)(wfb + (k + 3) * NH);
#pragma unroll
      for (int i = 0; i < 4; ++i) {
        float4 cv = *(const float4*)(sm + OFF_PREA + (jg + 16 * i) * PP + k);
        acc[i].x += cv.x * w0.x + cv.y * w1.x + cv.z * w2.x + cv.w * w3.x;
        acc[i].y += cv.x * w0.y + cv.y * w1.y + cv.z * w2.y + cv.w * w3.y;
        acc[i].z += cv.x * w0.z + cv.y * w1.z + cv.z * w2.z + cv.w * w3.z;
        acc[i].w += cv.x * w0.w + cv.y * w1.w + cv.z * w2.w + cv.w * w3.w;
      }
    }
    float4 u0 = *(const float4*)(sm + OFF_U + oq);
    float4 u1 = *(const float4*)(sm + OFF_U + NH + oq);
    float4 u2 = *(const float4*)(sm + OFF_U + 2 * NH + oq);
#pragma unroll
    for (int i = 0; i < 4; ++i) {
      int j = jg + 16 * i;
      int jm = (j > 0) ? (j - 1) : 0;  // row 0 unused; clamp avoids OOB
      float rx = sm[OFF_REFX + jm], ry = sm[OFF_REFY + jm];
      float4 r;
      r.x = acc[i].x + rx * u0.x + ry * u1.x + u2.x;
      r.y = acc[i].y + rx * u0.y + ry * u1.y + u2.y;
      r.z = acc[i].z + rx * u0.z + ry * u1.z + u2.z;
      r.w = acc[i].w + rx * u0.w + ry * u1.w + u2.w;
      *(float4*)(sm + OFF_ATTH + j * PP + oq) = r;
    }
  }
  __syncthreads();

  // ========== G: glogits[j][s] (k4-outer like C) ==========
  {
    const float* ph = sm + OFF_ATTH + jj * PP;
    float accv[8] = {0.f, 0.f, 0.f, 0.f, 0.f, 0.f, 0.f, 0.f};
#pragma unroll 2
    for (int k4 = 0; k4 < 32; ++k4) {
      float4 h = *(const float4*)(ph + 4 * k4);
      float4 v = *(const float4*)(sm + OFF_VPV + 4 * k4);
#pragma unroll
      for (int i = 0; i < 8; ++i) {
        float4 a = *(const float4*)(sm + OFF_PREP + (sq + 8 * i) * PP + 4 * k4);
        accv[i] += ftanh(a.x + h.x) * v.x + ftanh(a.y + h.y) * v.y +
                   ftanh(a.z + h.z) * v.z + ftanh(a.w + h.w) * v.w;
      }
    }
#pragma unroll
    for (int i = 0; i < 8; ++i) sm[OFF_SCOR + jj * SP + sq + 8 * i] = accv[i];
  }
  __syncthreads();

  // ========== H: masked log-softmax + argmax (first-index tie) + outputs =====
  {
    const float* lr = sm + OFF_SCOR + jj * SP + 8 * sq;
    float4 la = *(const float4*)(lr);
    float4 lb = *(const float4*)(lr + 4);
    float lg[8] = {la.x, la.y, la.z, la.w, lb.x, lb.y, lb.z, lb.w};
    float ml[8];
    float m = -INFINITY;
    int mi = 127;
#pragma unroll
    for (int i = 0; i < 8; ++i) {
      int s = 8 * sq + i;
      ml[i] = (ranki[s] >= jj) ? lg[i] : -INFINITY;  // mask excludes sol[0..j-1]
      if (ml[i] > m) { m = ml[i]; mi = s; }
    }
#pragma unroll
    for (int off = 1; off <= 4; off <<= 1) {
      float om = __shfl_xor(m, off);
      int oi = __shfl_xor(mi, off);
      if (om > m || (om == m && oi < mi)) { m = om; mi = oi; }
    }
    float ssum = 0.f;
#pragma unroll
    for (int i = 0; i < 8; ++i) ssum += __expf(ml[i] - m);
    ssum += __shfl_xor(ssum, 1); ssum += __shfl_xor(ssum, 2); ssum += __shfl_xor(ssum, 4);
    if (sq == 0 && jj >= 1) {
      out[b * NS + jj] = (float)mi;
      float pv = sm[OFF_SCOR + jj * SP + soli[jj]];  // sol[j] unmasked at step j
      out[NB * NS + b * NSTEPS + (jj - 1)] = pv - m - __logf(ssum);
    }
  }
}

extern "C" void kernel_launch(void* const* d_in, const int* in_sizes, int n_in,
                              void* d_out, int out_size, void* d_ws,
                              size_t ws_size, hipStream_t stream) {
  (void)in_sizes; (void)n_in; (void)out_size; (void)ws_size;
  const float* instance = (const float*)d_in[0];
  const int*   solution = (const int*)d_in[1];
  const float* Z        = (const float*)d_in[2];
  const float* IH       = (const float*)d_in[3];
  const float* last_hh  = (const float*)d_in[4];
  const float* W_emb    = (const float*)d_in[5];
  const float* b_emb    = (const float*)d_in[6];
  const float* W_ih     = (const float*)d_in[7];
  const float* W_hh     = (const float*)d_in[8];
  const float* b_ih     = (const float*)d_in[9];
  const float* b_hh     = (const float*)d_in[10];
  const float* W_a      = (const float*)d_in[11];
  const float* v_a      = (const float*)d_in[12];
  const float* W1       = (const float*)d_in[13];
  const float* b1       = (const float*)d_in[14];
  const float* W2       = (const float*)d_in[15];
  const float* b2       = (const float*)d_in[16];
  const float* Wp       = (const float*)d_in[17];
  const float* vp       = (const float*)d_in[18];
  float* out = (float*)d_out;
  float* gWf = (float*)d_ws;  // 64 KB scratch for folded MLP weight

  const int shmem = SM_FLOATS * 4;
  static_assert(SM_FLOATS * 4 <= 160 * 1024, "LDS overlay too big");
  hipFuncSetAttribute((const void*)decoder_kernel,
                      hipFuncAttributeMaxDynamicSharedMemorySize, shmem);
  decoder_kernel<<<NB, 512, shmem, stream>>>(
      instance, solution, Z, IH, last_hh, W_emb, b_emb, W_ih, W_hh, b_ih, b_hh,
      W_a, v_a, W1, b1, W2, b2, Wp, vp, gWf, out);
}

// Round 8
// 469.805 us; speedup vs baseline: 5.1340x; 1.0126x over previous
//
#include <hip/hip_runtime.h>
#include <math.h>

#define NB 256
#define NS 64
#define NH 128
#define NZ 128
#define NSTEPS 63
#define HP 144   // HALL row pitch (padh layout within each row)
#define PP 132   // preA/preP/atth(ptrh)/ctx row pitch
#define SP 68    // scores row pitch

// LDS float-offsets (total 39808 floats = 155.5 KiB)
#define OFF_PREA 0       // 8448
#define OFF_PREP 8448    // 8448 -> [0,16896)
#define OFF_HALL 16896   // 9216 -> [16896,26112)
#define OFF_ATTH 26112   // 8448 -> [26112,34560)
#define OFF_SCOR 34560   // 4352 -> [34560,38912)
#define OFF_U    38912   // 384
#define OFF_VA   39296   // 128
#define OFF_VPV  39424   // 128
#define OFF_REFX 39552   // 64
#define OFF_REFY 39616   // 64
#define OFF_SOL  39680   // 64 (int)
#define OFF_RANK 39744   // 64 (int)
#define SM_FLOATS 39808
// startup temps (regions free until their persistent users start):
#define OFF_S    16896   // S 16384 -> [16896,33280): HALL+ATTH, dead after Wf
#define OFF_IH   16896   // IH_lds 8192 -> [16896,25088): after S dead, before h0
#define OFF_GPRE 34560   // 1152 (SCOR region; SCOR first written after h-chain)
#define OFF_BHH  35712   // 384
#define OFF_AM   36096   // 768  (startup only)
#define OFF_V2   36864   // 384  (startup only)

// +4 pad per 32-float chunk (r1-validated conflict fix for HALL rows)
__device__ __forceinline__ int padh(int i) { return i + ((i >> 5) << 2); }

// fast tanh for the non-recurrent score paths (validated r1/r4/r5/r6/r7)
__device__ __forceinline__ float ftanh(float x) {
  float e = __expf(2.0f * x);
  return 1.0f - 2.0f * __builtin_amdgcn_rcpf(e + 1.0f);
}

// Teacher forcing => only the GRU h-chain is serial. Structure:
// startup (redundancy-free GEMMs) -> 63-iter h-chain (W_hh in VGPRs) ->
// 7 batched phases over all 63 steps.
// launch_bounds(512,1): LDS (155.5KB) already limits to 1 block/CU, so the
// 2-block guarantee bought nothing; min-waves=1 lifts the VGPR cap 128->256 so
// the 96-float W_hh cache can actually stay register-resident (the r1/r3/r6
// "compiler refuses" was the (512,2) 128-VGPR cap all along).
__global__ __launch_bounds__(512, 1) void decoder_kernel(
    const float* __restrict__ instance, const int* __restrict__ solution,
    const float* __restrict__ Z, const float* __restrict__ IH,
    const float* __restrict__ last_hh, const float* __restrict__ W_emb,
    const float* __restrict__ b_emb, const float* __restrict__ W_ih,
    const float* __restrict__ W_hh, const float* __restrict__ b_ih,
    const float* __restrict__ b_hh, const float* __restrict__ W_a,
    const float* __restrict__ v_a, const float* __restrict__ W1,
    const float* __restrict__ b1, const float* __restrict__ W2,
    const float* __restrict__ b2, const float* __restrict__ Wp,
    const float* __restrict__ vp, float* __restrict__ gWf,
    float* __restrict__ out) {
  extern __shared__ float sm[];
  int* soli = (int*)(sm + OFF_SOL);
  int* ranki = (int*)(sm + OFF_RANK);
  const int b = blockIdx.x;
  const int t = threadIdx.x;
  const float* ihb = IH + b * NS * NH;

  // ---------- thread-role constants ----------
  const int o4 = t >> 2, q4 = t & 3;        // h-chain: 128 outs x 4 k-chunks
  const int oq = (t & 31) * 4, jg = t >> 5; // GEMM phases B/D/P: o-quad x 16 j-strips
  const int jj = t >> 3, sq = t & 7;        // score phases C/G/softmax/H
  const int oS = t & 127, kq = t >> 7;      // startup GEMMs: 128 cols x 4 k-groups (kq wave-uniform)

  // ================= startup phase 0 =================
  if (t < NS) {
    int sv = solution[b * NS + t];
    soli[t] = sv;
    ranki[sv] = t;
    sm[OFF_REFX + t] = instance[(b * NS + sv) * 2 + 0];
    sm[OFF_REFY + t] = instance[(b * NS + sv) * 2 + 1];
  }
  if (t < NH) {
    sm[OFF_VA + t] = v_a[t];
    sm[OFF_VPV + t] = vp[t];
  }
  if (t < 384) sm[OFF_BHH + t] = b_hh[t];
  // Gpre[c][o3] = [W_emb;b_emb][c] . W_ih[o3,:]  (+ b_ih for c=2)
  if (t < 384) {
    const float* wi = W_ih + t * NH;
    float g0 = 0.f, g1 = 0.f, g2 = 0.f;
#pragma unroll 4
    for (int k4 = 0; k4 < 32; ++k4) {
      float4 w = *(const float4*)(wi + 4 * k4);
      float4 e0 = *(const float4*)(W_emb + 4 * k4);
      float4 e1 = *(const float4*)(W_emb + NH + 4 * k4);
      float4 eb = *(const float4*)(b_emb + 4 * k4);
      g0 += w.x * e0.x + w.y * e0.y + w.z * e0.z + w.w * e0.w;
      g1 += w.x * e1.x + w.y * e1.y + w.z * e1.z + w.w * e1.w;
      g2 += w.x * eb.x + w.y * eb.y + w.z * eb.z + w.w * eb.w;
    }
    sm[OFF_GPRE + t] = g0;
    sm[OFF_GPRE + 384 + t] = g1;
    sm[OFF_GPRE + 768 + t] = g2 + b_ih[t];
  }
  // am[c][m]: fc1 affine inputs (ref_h coords + Z/bias fold)
  if (t < 256) {
    const float* zb = Z + b * NZ;
    float a0 = 0.f, a1 = 0.f, a2 = 0.f;
#pragma unroll 2
    for (int k = 0; k < NH; ++k) {
      float wr = W1[(2 * NH + k) * 256 + t];
      a0 += W_emb[k] * wr;
      a1 += W_emb[NH + k] * wr;
      a2 += b_emb[k] * wr + zb[k] * W1[(NH + k) * 256 + t];
    }
    sm[OFF_AM + t] = a0;
    sm[OFF_AM + 256 + t] = a1;
    sm[OFF_AM + 512 + t] = a2 + b1[t];
  }
  // S[k][o] = W1[:H] @ W2, m-outer/acc[8]: W2 read once per 8-k strip (not 32x)
#pragma unroll 1
  for (int p = 0; p < 4; ++p) {
    const int kbase = kq * 32 + 8 * p;
    float acc[8] = {0.f, 0.f, 0.f, 0.f, 0.f, 0.f, 0.f, 0.f};
#pragma unroll 2
    for (int m4 = 0; m4 < 64; ++m4) {
      const int m = 4 * m4;
      float w2a = W2[(m + 0) * NH + oS];
      float w2b = W2[(m + 1) * NH + oS];
      float w2c = W2[(m + 2) * NH + oS];
      float w2d = W2[(m + 3) * NH + oS];
#pragma unroll
      for (int u = 0; u < 8; ++u) {
        float4 w1 = *(const float4*)(W1 + (kbase + u) * 256 + m);
        acc[u] += w1.x * w2a + w1.y * w2b + w1.z * w2c + w1.w * w2d;
      }
    }
#pragma unroll
    for (int u = 0; u < 8; ++u) sm[OFF_S + (kbase + u) * NH + oS] = acc[u];
  }
  __syncthreads();
  // ================= startup phase 1 =================
  // Wf[k][o] = S(LDS) @ Wp[H:], j-outer/acc[8]: Wp2 read once per 8-k strip
#pragma unroll 1
  for (int p = 0; p < 4; ++p) {
    const int kbase = kq * 32 + 8 * p;
    float acc[8] = {0.f, 0.f, 0.f, 0.f, 0.f, 0.f, 0.f, 0.f};
#pragma unroll 2
    for (int j4 = 0; j4 < 32; ++j4) {
      const int j = 4 * j4;
      float wpa = Wp[(NH + j + 0) * NH + oS];
      float wpb = Wp[(NH + j + 1) * NH + oS];
      float wpc = Wp[(NH + j + 2) * NH + oS];
      float wpd = Wp[(NH + j + 3) * NH + oS];
#pragma unroll
      for (int u = 0; u < 8; ++u) {
        float4 s4 = *(const float4*)(sm + OFF_S + (kbase + u) * NH + j);
        acc[u] += s4.x * wpa + s4.y * wpb + s4.z * wpc + s4.w * wpd;
      }
    }
#pragma unroll
    for (int u = 0; u < 8; ++u) gWf[(kbase + u) * NH + oS] = acc[u];
  }
  // v[c] = am[c] @ W2 (+ b2 for c=2)
  if (t < 384) {
    const int c = t >> 7, jc = t & 127;
    const float* amc = sm + OFF_AM + c * 256;
    float acc = (c == 2) ? b2[jc] : 0.f;
#pragma unroll 4
    for (int m = 0; m < 256; ++m) acc += amc[m] * W2[m * NH + jc];
    sm[OFF_V2 + t] = acc;
  }
  __syncthreads();
  // ================= startup phase 2 =================
  if (t < 384) {  // U[c] = v[c] @ Wp[H:]
    const int c = t >> 7, o = t & 127;
    const float* vc = sm + OFF_V2 + c * NH;
    float acc = 0.f;
#pragma unroll 4
    for (int j = 0; j < NH; ++j) acc += vc[j] * Wp[(NH + j) * NH + o];
    sm[OFF_U + c * NH + o] = acc;
  }
  // stage IH tile into LDS (coalesced; S region is dead now)
  for (int i = 4 * t; i < NS * NH; i += 2048)
    *(float4*)(sm + OFF_IH + i) = *(const float4*)(ihb + i);
  __syncthreads();
  // ================= startup phase 3 =================
  // preA/preP: k4-outer/acc[16]x2 — W_a/Wp rows read once (not 16x)
  {
    const int jx = t & 127, sg = t >> 7;  // sg wave-uniform
    float accA[16], accP[16];
#pragma unroll
    for (int si = 0; si < 16; ++si) { accA[si] = 0.f; accP[si] = 0.f; }
#pragma unroll 2
    for (int k4 = 0; k4 < 32; ++k4) {
      const int k = 4 * k4;
      float wa0 = W_a[(k + 0) * NH + jx];
      float wa1 = W_a[(k + 1) * NH + jx];
      float wa2 = W_a[(k + 2) * NH + jx];
      float wa3 = W_a[(k + 3) * NH + jx];
      float wp0 = Wp[(k + 0) * NH + jx];
      float wp1 = Wp[(k + 1) * NH + jx];
      float wp2 = Wp[(k + 2) * NH + jx];
      float wp3 = Wp[(k + 3) * NH + jx];
#pragma unroll
      for (int si = 0; si < 16; ++si) {
        float4 ih = *(const float4*)(sm + OFF_IH + (sg * 16 + si) * NH + k);
        accA[si] += ih.x * wa0 + ih.y * wa1 + ih.z * wa2 + ih.w * wa3;
        accP[si] += ih.x * wp0 + ih.y * wp1 + ih.z * wp2 + ih.w * wp3;
      }
    }
#pragma unroll
    for (int si = 0; si < 16; ++si) {
      sm[OFF_PREA + (sg * 16 + si) * PP + jx] = accA[si];
      sm[OFF_PREP + (sg * 16 + si) * PP + jx] = accP[si];
    }
  }
  if (t == 0) out[b * NS] = (float)soli[0];
  __syncthreads();
  // ================= startup phase 4: h0 (overwrites dead IH region) ========
  if (t < NH) sm[OFF_HALL + padh(t)] = last_hh[b * NH + t];
  __syncthreads();

  // ========== h-chain: the ONLY serial recurrence (63 iters, 1 barrier each).
  // W_hh register cache loaded HERE (narrow live range: spans only this loop,
  // not the acc[16]-heavy startup). 96 VGPRs + temps < 256 cap.
  {
    float4 whr[8], whz[8], whn[8];
    {
      const float* br = W_hh + (0 * NH + o4) * NH + 32 * q4;
      const float* bz = W_hh + (1 * NH + o4) * NH + 32 * q4;
      const float* bn = W_hh + (2 * NH + o4) * NH + 32 * q4;
#pragma unroll
      for (int u = 0; u < 8; ++u) {
        whr[u] = *(const float4*)(br + 4 * u);
        whz[u] = *(const float4*)(bz + 4 * u);
        whn[u] = *(const float4*)(bn + 4 * u);
      }
    }
    // hoist loop-invariant LDS scalars (compiler can't hoist across barriers)
    const float bhr = sm[OFF_BHH + o4];
    const float bhz = sm[OFF_BHH + NH + o4];
    const float bhn = sm[OFF_BHH + 2 * NH + o4];
    const float gr0 = sm[OFF_GPRE + o4];
    const float gr1 = sm[OFF_GPRE + 384 + o4];
    const float gr2 = sm[OFF_GPRE + 768 + o4];
    const float gz0 = sm[OFF_GPRE + NH + o4];
    const float gz1 = sm[OFF_GPRE + 384 + NH + o4];
    const float gz2 = sm[OFF_GPRE + 768 + NH + o4];
    const float gn0 = sm[OFF_GPRE + 2 * NH + o4];
    const float gn1 = sm[OFF_GPRE + 384 + 2 * NH + o4];
    const float gn2 = sm[OFF_GPRE + 768 + 2 * NH + o4];
#pragma unroll 1
    for (int j = 1; j <= NSTEPS; ++j) {
      float ar = 0.f, az = 0.f, an = 0.f;
      const float* hp = sm + OFF_HALL + (j - 1) * HP + 36 * q4;  // padh(32*q4)
#pragma unroll
      for (int u = 0; u < 8; ++u) {
        float4 hv = *(const float4*)(hp + 4 * u);
        ar += hv.x * whr[u].x + hv.y * whr[u].y + hv.z * whr[u].z + hv.w * whr[u].w;
        az += hv.x * whz[u].x + hv.y * whz[u].y + hv.z * whz[u].z + hv.w * whz[u].w;
        an += hv.x * whn[u].x + hv.y * whn[u].y + hv.z * whn[u].z + hv.w * whn[u].w;
      }
      ar += __shfl_xor(ar, 1); ar += __shfl_xor(ar, 2);
      az += __shfl_xor(az, 1); az += __shfl_xor(az, 2);
      an += __shfl_xor(an, 1); an += __shfl_xor(an, 2);
      if (q4 == 0) {
        float r0 = sm[OFF_REFX + (j - 1)], r1 = sm[OFF_REFY + (j - 1)];
        float gir = r0 * gr0 + r1 * gr1 + gr2;
        float giz = r0 * gz0 + r1 * gz1 + gz2;
        float gin = r0 * gn0 + r1 * gn1 + gn2;
        // recurrent path keeps libm precision (compounds over 63 steps)
        float r = 1.f / (1.f + expf(-(gir + ar + bhr)));
        float z = 1.f / (1.f + expf(-(giz + az + bhz)));
        float n = tanhf(gin + r * (an + bhn));
        float hold = sm[OFF_HALL + (j - 1) * HP + padh(o4)];
        sm[OFF_HALL + j * HP + padh(o4)] = (1.f - z) * n + z * hold;
      }
      __syncthreads();
    }
  }

  // ========== B: atthB[j] = h_j @ W_a[H:] (batched; W_a2 streamed L2) ==========
  {
    float4 acc[4];
#pragma unroll
    for (int i = 0; i < 4; ++i) acc[i] = (float4){0.f, 0.f, 0.f, 0.f};
    const float* wbase = W_a + NH * NH + oq;
#pragma unroll 4
    for (int k4 = 0; k4 < 32; ++k4) {
      int k = 4 * k4;
      int hoff = k + 4 * (k4 >> 3);  // padh offset (contiguous within 32-chunk)
      float4 w0 = *(const float4*)(wbase + (k + 0) * NH);
      float4 w1 = *(const float4*)(wbase + (k + 1) * NH);
      float4 w2 = *(const float4*)(wbase + (k + 2) * NH);
      float4 w3 = *(const float4*)(wbase + (k + 3) * NH);
#pragma unroll
      for (int i = 0; i < 4; ++i) {
        float4 hv = *(const float4*)(sm + OFF_HALL + (jg + 16 * i) * HP + hoff);
        acc[i].x += hv.x * w0.x + hv.y * w1.x + hv.z * w2.x + hv.w * w3.x;
        acc[i].y += hv.x * w0.y + hv.y * w1.y + hv.z * w2.y + hv.w * w3.y;
        acc[i].z += hv.x * w0.z + hv.y * w1.z + hv.z * w2.z + hv.w * w3.z;
        acc[i].w += hv.x * w0.w + hv.y * w1.w + hv.z * w2.w + hv.w * w3.w;
      }
    }
#pragma unroll
    for (int i = 0; i < 4; ++i)
      *(float4*)(sm + OFF_ATTH + (jg + 16 * i) * PP + oq) = acc[i];
  }
  __syncthreads();

  // ========== C: scores[j][s] (k4-outer: atth/va rows read once, not 8x) =====
  {
    const float* ah = sm + OFF_ATTH + jj * PP;
    float accv[8] = {0.f, 0.f, 0.f, 0.f, 0.f, 0.f, 0.f, 0.f};
#pragma unroll 2
    for (int k4 = 0; k4 < 32; ++k4) {
      float4 h = *(const float4*)(ah + 4 * k4);
      float4 v = *(const float4*)(sm + OFF_VA + 4 * k4);
#pragma unroll
      for (int i = 0; i < 8; ++i) {
        float4 a = *(const float4*)(sm + OFF_PREA + (sq + 8 * i) * PP + 4 * k4);
        accv[i] += ftanh(a.x + h.x) * v.x + ftanh(a.y + h.y) * v.y +
                   ftanh(a.z + h.z) * v.z + ftanh(a.w + h.w) * v.w;
      }
    }
#pragma unroll
    for (int i = 0; i < 8; ++i) sm[OFF_SCOR + jj * SP + sq + 8 * i] = accv[i];
  }
  __syncthreads();

  // ========== softmax over s (per j; 8-lane groups, in place) ==========
  {
    const float* sr = sm + OFF_SCOR + jj * SP + 8 * sq;
    float4 ea = *(const float4*)(sr);
    float4 eb = *(const float4*)(sr + 4);
    float e0 = ea.x, e1 = ea.y, e2 = ea.z, e3 = ea.w;
    float e4 = eb.x, e5 = eb.y, e6 = eb.z, e7 = eb.w;
    float m = fmaxf(fmaxf(fmaxf(e0, e1), fmaxf(e2, e3)),
                    fmaxf(fmaxf(e4, e5), fmaxf(e6, e7)));
    m = fmaxf(m, __shfl_xor(m, 1));
    m = fmaxf(m, __shfl_xor(m, 2));
    m = fmaxf(m, __shfl_xor(m, 4));
    float p0 = __expf(e0 - m), p1 = __expf(e1 - m), p2 = __expf(e2 - m), p3 = __expf(e3 - m);
    float p4 = __expf(e4 - m), p5 = __expf(e5 - m), p6 = __expf(e6 - m), p7 = __expf(e7 - m);
    float ssum = ((p0 + p1) + (p2 + p3)) + ((p4 + p5) + (p6 + p7));
    ssum += __shfl_xor(ssum, 1); ssum += __shfl_xor(ssum, 2); ssum += __shfl_xor(ssum, 4);
    float4 oa, ob2;
    oa.x = p0 / ssum; oa.y = p1 / ssum; oa.z = p2 / ssum; oa.w = p3 / ssum;
    ob2.x = p4 / ssum; ob2.y = p5 / ssum; ob2.z = p6 / ssum; ob2.w = p7 / ssum;
    *(float4*)(sm + OFF_SCOR + jj * SP + 8 * sq) = oa;
    *(float4*)(sm + OFF_SCOR + jj * SP + 8 * sq + 4) = ob2;
  }
  __syncthreads();

  // ========== D: ctx[j] = attn[j] @ IH (into preA buffer; IH from L2) ==========
  {
    float4 acc[4];
#pragma unroll
    for (int i = 0; i < 4; ++i) acc[i] = (float4){0.f, 0.f, 0.f, 0.f};
    const float* ibase = ihb + oq;
#pragma unroll 4
    for (int s4 = 0; s4 < 16; ++s4) {
      int s = 4 * s4;
      float4 x0 = *(const float4*)(ibase + (s + 0) * NH);
      float4 x1 = *(const float4*)(ibase + (s + 1) * NH);
      float4 x2 = *(const float4*)(ibase + (s + 2) * NH);
      float4 x3 = *(const float4*)(ibase + (s + 3) * NH);
#pragma unroll
      for (int i = 0; i < 4; ++i) {
        const float* at = sm + OFF_SCOR + (jg + 16 * i) * SP + s;
        float a0 = at[0], a1 = at[1], a2 = at[2], a3 = at[3];
        acc[i].x += a0 * x0.x + a1 * x1.x + a2 * x2.x + a3 * x3.x;
        acc[i].y += a0 * x0.y + a1 * x1.y + a2 * x2.y + a3 * x3.y;
        acc[i].z += a0 * x0.z + a1 * x1.z + a2 * x2.z + a3 * x3.z;
        acc[i].w += a0 * x0.w + a1 * x1.w + a2 * x2.w + a3 * x3.w;
      }
    }
#pragma unroll
    for (int i = 0; i < 4; ++i)
      *(float4*)(sm + OFF_PREA + (jg + 16 * i) * PP + oq) = acc[i];
  }
  __syncthreads();

  // ========== P: ptrh[j] = ctx[j] @ Wf + affine (into atth buffer) ==========
  {
    float4 acc[4];
#pragma unroll
    for (int i = 0; i < 4; ++i) acc[i] = (float4){0.f, 0.f, 0.f, 0.f};
    const float* wfb = gWf + oq;
#pragma unroll 4
    for (int k4 = 0; k4 < 32; ++k4) {
      int k = 4 * k4;
      float4 w0 = *(const float4*)(wfb + (k + 0) * NH);
      float4 w1 = *(const float4*)(wfb + (k + 1) * NH);
      float4 w2 = *(const float4*)(wfb + (k + 2) * NH);
      float4 w3 = *(const float4*)(wfb + (k + 3) * NH);
#pragma unroll
      for (int i = 0; i < 4; ++i) {
        float4 cv = *(const float4*)(sm + OFF_PREA + (jg + 16 * i) * PP + k);
        acc[i].x += cv.x * w0.x + cv.y * w1.x + cv.z * w2.x + cv.w * w3.x;
        acc[i].y += cv.x * w0.y + cv.y * w1.y + cv.z * w2.y + cv.w * w3.y;
        acc[i].z += cv.x * w0.z + cv.y * w1.z + cv.z * w2.z + cv.w * w3.z;
        acc[i].w += cv.x * w0.w + cv.y * w1.w + cv.z * w2.w + cv.w * w3.w;
      }
    }
    float4 u0 = *(const float4*)(sm + OFF_U + oq);
    float4 u1 = *(const float4*)(sm + OFF_U + NH + oq);
    float4 u2 = *(const float4*)(sm + OFF_U + 2 * NH + oq);
#pragma unroll
    for (int i = 0; i < 4; ++i) {
      int j = jg + 16 * i;
      int jm = (j > 0) ? (j - 1) : 0;  // row 0 unused; clamp avoids OOB
      float rx = sm[OFF_REFX + jm], ry = sm[OFF_REFY + jm];
      float4 r;
      r.x = acc[i].x + rx * u0.x + ry * u1.x + u2.x;
      r.y = acc[i].y + rx * u0.y + ry * u1.y + u2.y;
      r.z = acc[i].z + rx * u0.z + ry * u1.z + u2.z;
      r.w = acc[i].w + rx * u0.w + ry * u1.w + u2.w;
      *(float4*)(sm + OFF_ATTH + j * PP + oq) = r;
    }
  }
  __syncthreads();

  // ========== G: glogits[j][s] (k4-outer like C) ==========
  {
    const float* ph = sm + OFF_ATTH + jj * PP;
    float accv[8] = {0.f, 0.f, 0.f, 0.f, 0.f, 0.f, 0.f, 0.f};
#pragma unroll 2
    for (int k4 = 0; k4 < 32; ++k4) {
      float4 h = *(const float4*)(ph + 4 * k4);
      float4 v = *(const float4*)(sm + OFF_VPV + 4 * k4);
#pragma unroll
      for (int i = 0; i < 8; ++i) {
        float4 a = *(const float4*)(sm + OFF_PREP + (sq + 8 * i) * PP + 4 * k4);
        accv[i] += ftanh(a.x + h.x) * v.x + ftanh(a.y + h.y) * v.y +
                   ftanh(a.z + h.z) * v.z + ftanh(a.w + h.w) * v.w;
      }
    }
#pragma unroll
    for (int i = 0; i < 8; ++i) sm[OFF_SCOR + jj * SP + sq + 8 * i] = accv[i];
  }
  __syncthreads();

  // ========== H: masked log-softmax + argmax (first-index tie) + outputs =====
  {
    const float* lr = sm + OFF_SCOR + jj * SP + 8 * sq;
    float4 la = *(const float4*)(lr);
    float4 lb = *(const float4*)(lr + 4);
    float lg[8] = {la.x, la.y, la.z, la.w, lb.x, lb.y, lb.z, lb.w};
    float ml[8];
    float m = -INFINITY;
    int mi = 127;
#pragma unroll
    for (int i = 0; i < 8; ++i) {
      int s = 8 * sq + i;
      ml[i] = (ranki[s] >= jj) ? lg[i] : -INFINITY;  // mask excludes sol[0..j-1]
      if (ml[i] > m) { m = ml[i]; mi = s; }
    }
#pragma unroll
    for (int off = 1; off <= 4; off <<= 1) {
      float om = __shfl_xor(m, off);
      int oi = __shfl_xor(mi, off);
      if (om > m || (om == m && oi < mi)) { m = om; mi = oi; }
    }
    float ssum = 0.f;
#pragma unroll
    for (int i = 0; i < 8; ++i) ssum += __expf(ml[i] - m);
    ssum += __shfl_xor(ssum, 1); ssum += __shfl_xor(ssum, 2); ssum += __shfl_xor(ssum, 4);
    if (sq == 0 && jj >= 1) {
      out[b * NS + jj] = (float)mi;
      float pv = sm[OFF_SCOR + jj * SP + soli[jj]];  // sol[j] unmasked at step j
      out[NB * NS + b * NSTEPS + (jj - 1)] = pv - m - __logf(ssum);
    }
  }
}

extern "C" void kernel_launch(void* const* d_in, const int* in_sizes, int n_in,
                              void* d_out, int out_size, void* d_ws,
                              size_t ws_size, hipStream_t stream) {
  (void)in_sizes; (void)n_in; (void)out_size; (void)ws_size;
  const float* instance = (const float*)d_in[0];
  const int*   solution = (const int*)d_in[1];
  const float* Z        = (const float*)d_in[2];
  const float* IH       = (const float*)d_in[3];
  const float* last_hh  = (const float*)d_in[4];
  const float* W_emb    = (const float*)d_in[5];
  const float* b_emb    = (const float*)d_in[6];
  const float* W_ih     = (const float*)d_in[7];
  const float* W_hh     = (const float*)d_in[8];
  const float* b_ih     = (const float*)d_in[9];
  const float* b_hh     = (const float*)d_in[10];
  const float* W_a      = (const float*)d_in[11];
  const float* v_a      = (const float*)d_in[12];
  const float* W1       = (const float*)d_in[13];
  const float* b1       = (const float*)d_in[14];
  const float* W2       = (const float*)d_in[15];
  const float* b2       = (const float*)d_in[16];
  const float* Wp       = (const float*)d_in[17];
  const float* vp       = (const float*)d_in[18];
  float* out = (float*)d_out;
  float* gWf = (float*)d_ws;  // 64 KB scratch for folded MLP weight

  const int shmem = SM_FLOATS * 4;
  static_assert(SM_FLOATS * 4 <= 160 * 1024, "LDS overlay too big");
  hipFuncSetAttribute((const void*)decoder_kernel,
                      hipFuncAttributeMaxDynamicSharedMemorySize, shmem);
  decoder_kernel<<<NB, 512, shmem, stream>>>(
      instance, solution, Z, IH, last_hh, W_emb, b_emb, W_ih, W_hh, b_ih, b_hh,
      W_a, v_a, W1, b1, W2, b2, Wp, vp, gWf, out);
}

// Round 9
// 366.877 us; speedup vs baseline: 6.5744x; 1.2806x over previous
//
#include <hip/hip_runtime.h>
#include <math.h>

#define NB 256
#define NS 64
#define NH 128
#define NZ 128
#define NSTEPS 63
#define HP 144   // HALL row pitch (padh layout within each row)
#define PP 132   // preA/preP/atth(ptrh)/ctx row pitch
#define SP 68    // scores row pitch

// LDS float-offsets (total 39808 floats = 155.5 KiB)
#define OFF_PREA 0       // 8448 (post-chain; WN lives here during startup+chain)
#define OFF_PREP 8448    // 8448 -> [0,16896)
#define OFF_WN   0       // 512*33 = 16896: gate-n weights, per-thread slice (chain only)
#define OFF_HALL 16896   // 9216 -> [16896,26112)
#define OFF_ATTH 26112   // 8448 -> [26112,34560); post-chain: IH stage, then atth/ptrh
#define OFF_SCOR 34560   // 4352 -> [34560,38912)
#define OFF_U    38912   // 384
#define OFF_VA   39296   // 128
#define OFF_VPV  39424   // 128
#define OFF_REFX 39552   // 64
#define OFF_REFY 39616   // 64
#define OFF_SOL  39680   // 64 (int)
#define OFF_RANK 39744   // 64 (int)
#define SM_FLOATS 39808
// startup temps inside SCOR region (dead before SCOR first written):
#define OFF_GPRE 34560   // 1152
#define OFF_BHH  35712   // 384
#define OFF_AM   36096   // 768
#define OFF_V2   36864   // 384

// +4 pad per 32-float chunk (r1-validated conflict fix for HALL rows)
__device__ __forceinline__ int padh(int i) { return i + ((i >> 5) << 2); }

// fast tanh for the non-recurrent score paths (validated r1/r4-r8)
__device__ __forceinline__ float ftanh(float x) {
  float e = __expf(2.0f * x);
  return 1.0f - 2.0f * __builtin_amdgcn_rcpf(e + 1.0f);
}

// pin 8 scalar floats into VGPRs: asm results can't be rematerialized-by-reload
#define PIN8(a, i)                                                          \
  asm volatile("" : "+v"((a)[(i)]), "+v"((a)[(i) + 1]), "+v"((a)[(i) + 2]), \
                    "+v"((a)[(i) + 3]), "+v"((a)[(i) + 4]),                 \
                    "+v"((a)[(i) + 5]), "+v"((a)[(i) + 6]),                 \
                    "+v"((a)[(i) + 7]))

// ---- pre-kernel: shared fold Wf = (W1[:H] @ W2) @ Wp[H:], computed ONCE ----
// (was redundantly recomputed by all 256 blocks = ~22K instr/thread each)
__global__ __launch_bounds__(128, 1) void fold_kernel(
    const float* __restrict__ W1, const float* __restrict__ W2,
    const float* __restrict__ Wp, float* __restrict__ gWf) {
  __shared__ float srow[NH];
  const int g = blockIdx.x;   // k-row 0..127
  const int o = threadIdx.x;  // 0..127
  const float* w1r = W1 + g * 256;
  float acc = 0.f;
#pragma unroll 8
  for (int m = 0; m < 256; ++m) acc += w1r[m] * W2[m * NH + o];
  srow[o] = acc;
  __syncthreads();
  float wf = 0.f;
#pragma unroll 8
  for (int j = 0; j < NH; ++j) wf += srow[j] * Wp[(NH + j) * NH + o];
  gWf[g * NH + o] = wf;
}

// Teacher forcing => only the GRU h-chain is serial. Structure:
// startup (per-b pieces only) -> 63-iter h-chain (gate-n in LDS, gates r/z
// pinned in VGPRs) -> IH stage -> preA/preP -> 7 batched phases.
__global__ __launch_bounds__(512, 1) void decoder_kernel(
    const float* __restrict__ instance, const int* __restrict__ solution,
    const float* __restrict__ Z, const float* __restrict__ IH,
    const float* __restrict__ last_hh, const float* __restrict__ W_emb,
    const float* __restrict__ b_emb, const float* __restrict__ W_ih,
    const float* __restrict__ W_hh, const float* __restrict__ b_ih,
    const float* __restrict__ b_hh, const float* __restrict__ W_a,
    const float* __restrict__ v_a, const float* __restrict__ W1,
    const float* __restrict__ b1, const float* __restrict__ W2,
    const float* __restrict__ b2, const float* __restrict__ Wp,
    const float* __restrict__ vp, float* __restrict__ gWf,
    float* __restrict__ out) {
  extern __shared__ float sm[];
  int* soli = (int*)(sm + OFF_SOL);
  int* ranki = (int*)(sm + OFF_RANK);
  const int b = blockIdx.x;
  const int t = threadIdx.x;
  const float* ihb = IH + b * NS * NH;

  // ---------- thread-role constants ----------
  const int o4 = t >> 2, q4 = t & 3;        // h-chain: 128 outs x 4 k-chunks
  const int oq = (t & 31) * 4, jg = t >> 5; // GEMM phases B/D/P: o-quad x 16 j-strips
  const int jj = t >> 3, sq = t & 7;        // score phases C/G/softmax/H

  // ================= startup phase 0 =================
  if (t < NS) {
    int sv = solution[b * NS + t];
    soli[t] = sv;
    ranki[sv] = t;
    sm[OFF_REFX + t] = instance[(b * NS + sv) * 2 + 0];
    sm[OFF_REFY + t] = instance[(b * NS + sv) * 2 + 1];
  }
  if (t < NH) {
    sm[OFF_VA + t] = v_a[t];
    sm[OFF_VPV + t] = vp[t];
    sm[OFF_HALL + padh(t)] = last_hh[b * NH + t];  // h0 (HALL free in startup now)
  }
  if (t < 384) sm[OFF_BHH + t] = b_hh[t];
  // gate-n weights -> LDS, per-thread 32-float slice, pitch 33 (2 lanes/bank: free)
  {
    const float* wnp = W_hh + (2 * NH + o4) * NH + 32 * q4;
#pragma unroll 8
    for (int u = 0; u < 32; ++u) sm[OFF_WN + t * 33 + u] = wnp[u];
  }
  // Gpre[c][o3] = [W_emb;b_emb][c] . W_ih[o3,:]  (+ b_ih for c=2)
  if (t < 384) {
    const float* wi = W_ih + t * NH;
    float g0 = 0.f, g1 = 0.f, g2 = 0.f;
#pragma unroll 4
    for (int k4 = 0; k4 < 32; ++k4) {
      float4 w = *(const float4*)(wi + 4 * k4);
      float4 e0 = *(const float4*)(W_emb + 4 * k4);
      float4 e1 = *(const float4*)(W_emb + NH + 4 * k4);
      float4 eb = *(const float4*)(b_emb + 4 * k4);
      g0 += w.x * e0.x + w.y * e0.y + w.z * e0.z + w.w * e0.w;
      g1 += w.x * e1.x + w.y * e1.y + w.z * e1.z + w.w * e1.w;
      g2 += w.x * eb.x + w.y * eb.y + w.z * eb.z + w.w * eb.w;
    }
    sm[OFF_GPRE + t] = g0;
    sm[OFF_GPRE + 384 + t] = g1;
    sm[OFF_GPRE + 768 + t] = g2 + b_ih[t];
  }
  // am[c][m]: fc1 affine inputs (ref_h coords + Z/bias fold)
  if (t < 256) {
    const float* zb = Z + b * NZ;
    float a0 = 0.f, a1 = 0.f, a2 = 0.f;
#pragma unroll 2
    for (int k = 0; k < NH; ++k) {
      float wr = W1[(2 * NH + k) * 256 + t];
      a0 += W_emb[k] * wr;
      a1 += W_emb[NH + k] * wr;
      a2 += b_emb[k] * wr + zb[k] * W1[(NH + k) * 256 + t];
    }
    sm[OFF_AM + t] = a0;
    sm[OFF_AM + 256 + t] = a1;
    sm[OFF_AM + 512 + t] = a2 + b1[t];
  }
  __syncthreads();
  // ================= startup phase 1: v[c] = am[c] @ W2 (+ b2 for c=2) ======
  if (t < 384) {
    const int c = t >> 7, jc = t & 127;
    const float* amc = sm + OFF_AM + c * 256;
    float acc = (c == 2) ? b2[jc] : 0.f;
#pragma unroll 4
    for (int m = 0; m < 256; ++m) acc += amc[m] * W2[m * NH + jc];
    sm[OFF_V2 + t] = acc;
  }
  __syncthreads();
  // ================= startup phase 2: U[c] = v[c] @ Wp[H:] ==================
  if (t < 384) {
    const int c = t >> 7, o = t & 127;
    const float* vc = sm + OFF_V2 + c * NH;
    float acc = 0.f;
#pragma unroll 4
    for (int j = 0; j < NH; ++j) acc += vc[j] * Wp[(NH + j) * NH + o];
    sm[OFF_U + c * NH + o] = acc;
  }
  if (t == 0) out[b * NS] = (float)soli[0];
  __syncthreads();

  // ========== h-chain: the ONLY serial recurrence (63 iters, 1 barrier each).
  // Gates r,z: 64 scalar floats PINNED in VGPRs (64+~60 temps << 256 cap, pins
  // die before the acc[16]-heavy preA/preP phase). Gate n: LDS slice (WN).
  {
    float whr[32], whz[32];
    {
      const float* br = W_hh + (0 * NH + o4) * NH + 32 * q4;
      const float* bz = W_hh + (1 * NH + o4) * NH + 32 * q4;
#pragma unroll 8
      for (int u = 0; u < 32; ++u) { whr[u] = br[u]; whz[u] = bz[u]; }
    }
    PIN8(whr, 0); PIN8(whr, 8); PIN8(whr, 16); PIN8(whr, 24);
    PIN8(whz, 0); PIN8(whz, 8); PIN8(whz, 16); PIN8(whz, 24);
    const float* wn = sm + OFF_WN + t * 33;
    // hoist loop-invariant LDS scalars (compiler can't hoist across barriers)
    const float bhr = sm[OFF_BHH + o4];
    const float bhz = sm[OFF_BHH + NH + o4];
    const float bhn = sm[OFF_BHH + 2 * NH + o4];
    const float gr0 = sm[OFF_GPRE + o4];
    const float gr1 = sm[OFF_GPRE + 384 + o4];
    const float gr2 = sm[OFF_GPRE + 768 + o4];
    const float gz0 = sm[OFF_GPRE + NH + o4];
    const float gz1 = sm[OFF_GPRE + 384 + NH + o4];
    const float gz2 = sm[OFF_GPRE + 768 + NH + o4];
    const float gn0 = sm[OFF_GPRE + 2 * NH + o4];
    const float gn1 = sm[OFF_GPRE + 384 + 2 * NH + o4];
    const float gn2 = sm[OFF_GPRE + 768 + 2 * NH + o4];
#pragma unroll 1
    for (int j = 1; j <= NSTEPS; ++j) {
      float ar = 0.f, az = 0.f, an = 0.f;
      const float* hp = sm + OFF_HALL + (j - 1) * HP + 36 * q4;  // padh(32*q4)
#pragma unroll
      for (int u = 0; u < 8; ++u) {
        float4 hv = *(const float4*)(hp + 4 * u);
        ar += hv.x * whr[4 * u] + hv.y * whr[4 * u + 1] +
              hv.z * whr[4 * u + 2] + hv.w * whr[4 * u + 3];
        az += hv.x * whz[4 * u] + hv.y * whz[4 * u + 1] +
              hv.z * whz[4 * u + 2] + hv.w * whz[4 * u + 3];
        an += hv.x * wn[4 * u] + hv.y * wn[4 * u + 1] +
              hv.z * wn[4 * u + 2] + hv.w * wn[4 * u + 3];
      }
      ar += __shfl_xor(ar, 1); ar += __shfl_xor(ar, 2);
      az += __shfl_xor(az, 1); az += __shfl_xor(az, 2);
      an += __shfl_xor(an, 1); an += __shfl_xor(an, 2);
      if (q4 == 0) {
        float r0 = sm[OFF_REFX + (j - 1)], r1 = sm[OFF_REFY + (j - 1)];
        float gir = r0 * gr0 + r1 * gr1 + gr2;
        float giz = r0 * gz0 + r1 * gz1 + gz2;
        float gin = r0 * gn0 + r1 * gn1 + gn2;
        // recurrent path keeps libm precision (compounds over 63 steps)
        float r = 1.f / (1.f + expf(-(gir + ar + bhr)));
        float z = 1.f / (1.f + expf(-(giz + az + bhz)));
        float n = tanhf(gin + r * (an + bhn));
        float hold = sm[OFF_HALL + (j - 1) * HP + padh(o4)];
        sm[OFF_HALL + j * HP + padh(o4)] = (1.f - z) * n + z * hold;
      }
      __syncthreads();
    }
  }

  // ========== stage IH into ATTH region (WN/preA region about to be rebuilt) =
  for (int i = 4 * t; i < NS * NH; i += 2048)
    *(float4*)(sm + OFF_ATTH + i) = *(const float4*)(ihb + i);
  __syncthreads();
  // ========== preA/preP (deferred; overwrites dead WN region) ==========
  {
    const int jx = t & 127, sg = t >> 7;  // sg wave-uniform
    float accA[16], accP[16];
#pragma unroll
    for (int si = 0; si < 16; ++si) { accA[si] = 0.f; accP[si] = 0.f; }
#pragma unroll 2
    for (int k4 = 0; k4 < 32; ++k4) {
      const int k = 4 * k4;
      float wa0 = W_a[(k + 0) * NH + jx];
      float wa1 = W_a[(k + 1) * NH + jx];
      float wa2 = W_a[(k + 2) * NH + jx];
      float wa3 = W_a[(k + 3) * NH + jx];
      float wp0 = Wp[(k + 0) * NH + jx];
      float wp1 = Wp[(k + 1) * NH + jx];
      float wp2 = Wp[(k + 2) * NH + jx];
      float wp3 = Wp[(k + 3) * NH + jx];
#pragma unroll
      for (int si = 0; si < 16; ++si) {
        float4 ih = *(const float4*)(sm + OFF_ATTH + (sg * 16 + si) * NH + k);
        accA[si] += ih.x * wa0 + ih.y * wa1 + ih.z * wa2 + ih.w * wa3;
        accP[si] += ih.x * wp0 + ih.y * wp1 + ih.z * wp2 + ih.w * wp3;
      }
    }
#pragma unroll
    for (int si = 0; si < 16; ++si) {
      sm[OFF_PREA + (sg * 16 + si) * PP + jx] = accA[si];
      sm[OFF_PREP + (sg * 16 + si) * PP + jx] = accP[si];
    }
  }
  __syncthreads();

  // ========== B: atthB[j] = h_j @ W_a[H:] (batched; W_a2 streamed L2) ==========
  {
    float4 acc[4];
#pragma unroll
    for (int i = 0; i < 4; ++i) acc[i] = (float4){0.f, 0.f, 0.f, 0.f};
    const float* wbase = W_a + NH * NH + oq;
#pragma unroll 4
    for (int k4 = 0; k4 < 32; ++k4) {
      int k = 4 * k4;
      int hoff = k + 4 * (k4 >> 3);  // padh offset (contiguous within 32-chunk)
      float4 w0 = *(const float4*)(wbase + (k + 0) * NH);
      float4 w1 = *(const float4*)(wbase + (k + 1) * NH);
      float4 w2 = *(const float4*)(wbase + (k + 2) * NH);
      float4 w3 = *(const float4*)(wbase + (k + 3) * NH);
#pragma unroll
      for (int i = 0; i < 4; ++i) {
        float4 hv = *(const float4*)(sm + OFF_HALL + (jg + 16 * i) * HP + hoff);
        acc[i].x += hv.x * w0.x + hv.y * w1.x + hv.z * w2.x + hv.w * w3.x;
        acc[i].y += hv.x * w0.y + hv.y * w1.y + hv.z * w2.y + hv.w * w3.y;
        acc[i].z += hv.x * w0.z + hv.y * w1.z + hv.z * w2.z + hv.w * w3.z;
        acc[i].w += hv.x * w0.w + hv.y * w1.w + hv.z * w2.w + hv.w * w3.w;
      }
    }
#pragma unroll
    for (int i = 0; i < 4; ++i)
      *(float4*)(sm + OFF_ATTH + (jg + 16 * i) * PP + oq) = acc[i];
  }
  __syncthreads();

  // ========== C: scores[j][s] (k4-outer) ==========
  {
    const float* ah = sm + OFF_ATTH + jj * PP;
    float accv[8] = {0.f, 0.f, 0.f, 0.f, 0.f, 0.f, 0.f, 0.f};
#pragma unroll 2
    for (int k4 = 0; k4 < 32; ++k4) {
      float4 h = *(const float4*)(ah + 4 * k4);
      float4 v = *(const float4*)(sm + OFF_VA + 4 * k4);
#pragma unroll
      for (int i = 0; i < 8; ++i) {
        float4 a = *(const float4*)(sm + OFF_PREA + (sq + 8 * i) * PP + 4 * k4);
        accv[i] += ftanh(a.x + h.x) * v.x + ftanh(a.y + h.y) * v.y +
                   ftanh(a.z + h.z) * v.z + ftanh(a.w + h.w) * v.w;
      }
    }
#pragma unroll
    for (int i = 0; i < 8; ++i) sm[OFF_SCOR + jj * SP + sq + 8 * i] = accv[i];
  }
  __syncthreads();

  // ========== softmax over s (per j; 8-lane groups, in place) ==========
  {
    const float* sr = sm + OFF_SCOR + jj * SP + 8 * sq;
    float4 ea = *(const float4*)(sr);
    float4 eb = *(const float4*)(sr + 4);
    float e0 = ea.x, e1 = ea.y, e2 = ea.z, e3 = ea.w;
    float e4 = eb.x, e5 = eb.y, e6 = eb.z, e7 = eb.w;
    float m = fmaxf(fmaxf(fmaxf(e0, e1), fmaxf(e2, e3)),
                    fmaxf(fmaxf(e4, e5), fmaxf(e6, e7)));
    m = fmaxf(m, __shfl_xor(m, 1));
    m = fmaxf(m, __shfl_xor(m, 2));
    m = fmaxf(m, __shfl_xor(m, 4));
    float p0 = __expf(e0 - m), p1 = __expf(e1 - m), p2 = __expf(e2 - m), p3 = __expf(e3 - m);
    float p4 = __expf(e4 - m), p5 = __expf(e5 - m), p6 = __expf(e6 - m), p7 = __expf(e7 - m);
    float ssum = ((p0 + p1) + (p2 + p3)) + ((p4 + p5) + (p6 + p7));
    ssum += __shfl_xor(ssum, 1); ssum += __shfl_xor(ssum, 2); ssum += __shfl_xor(ssum, 4);
    float4 oa, ob2;
    oa.x = p0 / ssum; oa.y = p1 / ssum; oa.z = p2 / ssum; oa.w = p3 / ssum;
    ob2.x = p4 / ssum; ob2.y = p5 / ssum; ob2.z = p6 / ssum; ob2.w = p7 / ssum;
    *(float4*)(sm + OFF_SCOR + jj * SP + 8 * sq) = oa;
    *(float4*)(sm + OFF_SCOR + jj * SP + 8 * sq + 4) = ob2;
  }
  __syncthreads();

  // ========== D: ctx[j] = attn[j] @ IH (into preA buffer; IH from L2) ==========
  {
    float4 acc[4];
#pragma unroll
    for (int i = 0; i < 4; ++i) acc[i] = (float4){0.f, 0.f, 0.f, 0.f};
    const float* ibase = ihb + oq;
#pragma unroll 4
    for (int s4 = 0; s4 < 16; ++s4) {
      int s = 4 * s4;
      float4 x0 = *(const float4*)(ibase + (s + 0) * NH);
      float4 x1 = *(const float4*)(ibase + (s + 1) * NH);
      float4 x2 = *(const float4*)(ibase + (s + 2) * NH);
      float4 x3 = *(const float4*)(ibase + (s + 3) * NH);
#pragma unroll
      for (int i = 0; i < 4; ++i) {
        const float* at = sm + OFF_SCOR + (jg + 16 * i) * SP + s;
        float a0 = at[0], a1 = at[1], a2 = at[2], a3 = at[3];
        acc[i].x += a0 * x0.x + a1 * x1.x + a2 * x2.x + a3 * x3.x;
        acc[i].y += a0 * x0.y + a1 * x1.y + a2 * x2.y + a3 * x3.y;
        acc[i].z += a0 * x0.z + a1 * x1.z + a2 * x2.z + a3 * x3.z;
        acc[i].w += a0 * x0.w + a1 * x1.w + a2 * x2.w + a3 * x3.w;
      }
    }
#pragma unroll
    for (int i = 0; i < 4; ++i)
      *(float4*)(sm + OFF_PREA + (jg + 16 * i) * PP + oq) = acc[i];
  }
  __syncthreads();

  // ========== P: ptrh[j] = ctx[j] @ Wf + affine (into atth buffer) ==========
  {
    float4 acc[4];
#pragma unroll
    for (int i = 0; i < 4; ++i) acc[i] = (float4){0.f, 0.f, 0.f, 0.f};
    const float* wfb = gWf + oq;
#pragma unroll 4
    for (int k4 = 0; k4 < 32; ++k4) {
      int k = 4 * k4;
      float4 w0 = *(const float4*)(wfb + (k + 0) * NH);
      float4 w1 = *(const float4*)(wfb + (k + 1) * NH);
      float4 w2 = *(const float4*)(wfb + (k + 2) * NH);
      float4 w3 = *(const float4*)(wfb + (k + 3) * NH);
#pragma unroll
      for (int i = 0; i < 4; ++i) {
        float4 cv = *(const float4*)(sm + OFF_PREA + (jg + 16 * i) * PP + k);
        acc[i].x += cv.x * w0.x + cv.y * w1.x + cv.z * w2.x + cv.w * w3.x;
        acc[i].y += cv.x * w0.y + cv.y * w1.y + cv.z * w2.y + cv.w * w3.y;
        acc[i].z += cv.x * w0.z + cv.y * w1.z + cv.z * w2.z + cv.w * w3.z;
        acc[i].w += cv.x * w0.w + cv.y * w1.w + cv.z * w2.w + cv.w * w3.w;
      }
    }
    float4 u0 = *(const float4*)(sm + OFF_U + oq);
    float4 u1 = *(const float4*)(sm + OFF_U + NH + oq);
    float4 u2 = *(const float4*)(sm + OFF_U + 2 * NH + oq);
#pragma unroll
    for (int i = 0; i < 4; ++i) {
      int j = jg + 16 * i;
      int jm = (j > 0) ? (j - 1) : 0;  // row 0 unused; clamp avoids OOB
      float rx = sm[OFF_REFX + jm], ry = sm[OFF_REFY + jm];
      float4 r;
      r.x = acc[i].x + rx * u0.x + ry * u1.x + u2.x;
      r.y = acc[i].y + rx * u0.y + ry * u1.y + u2.y;
      r.z = acc[i].z + rx * u0.z + ry * u1.z + u2.z;
      r.w = acc[i].w + rx * u0.w + ry * u1.w + u2.w;
      *(float4*)(sm + OFF_ATTH + j * PP + oq) = r;
    }
  }
  __syncthreads();

  // ========== G: glogits[j][s] (k4-outer like C) ==========
  {
    const float* ph = sm + OFF_ATTH + jj * PP;
    float accv[8] = {0.f, 0.f, 0.f, 0.f, 0.f, 0.f, 0.f, 0.f};
#pragma unroll 2
    for (int k4 = 0; k4 < 32; ++k4) {
      float4 h = *(const float4*)(ph + 4 * k4);
      float4 v = *(const float4*)(sm + OFF_VPV + 4 * k4);
#pragma unroll
      for (int i = 0; i < 8; ++i) {
        float4 a = *(const float4*)(sm + OFF_PREP + (sq + 8 * i) * PP + 4 * k4);
        accv[i] += ftanh(a.x + h.x) * v.x + ftanh(a.y + h.y) * v.y +
                   ftanh(a.z + h.z) * v.z + ftanh(a.w + h.w) * v.w;
      }
    }
#pragma unroll
    for (int i = 0; i < 8; ++i) sm[OFF_SCOR + jj * SP + sq + 8 * i] = accv[i];
  }
  __syncthreads();

  // ========== H: masked log-softmax + argmax (first-index tie) + outputs =====
  {
    const float* lr = sm + OFF_SCOR + jj * SP + 8 * sq;
    float4 la = *(const float4*)(lr);
    float4 lb = *(const float4*)(lr + 4);
    float lg[8] = {la.x, la.y, la.z, la.w, lb.x, lb.y, lb.z, lb.w};
    float ml[8];
    float m = -INFINITY;
    int mi = 127;
#pragma unroll
    for (int i = 0; i < 8; ++i) {
      int s = 8 * sq + i;
      ml[i] = (ranki[s] >= jj) ? lg[i] : -INFINITY;  // mask excludes sol[0..j-1]
      if (ml[i] > m) { m = ml[i]; mi = s; }
    }
#pragma unroll
    for (int off = 1; off <= 4; off <<= 1) {
      float om = __shfl_xor(m, off);
      int oi = __shfl_xor(mi, off);
      if (om > m || (om == m && oi < mi)) { m = om; mi = oi; }
    }
    float ssum = 0.f;
#pragma unroll
    for (int i = 0; i < 8; ++i) ssum += __expf(ml[i] - m);
    ssum += __shfl_xor(ssum, 1); ssum += __shfl_xor(ssum, 2); ssum += __shfl_xor(ssum, 4);
    if (sq == 0 && jj >= 1) {
      out[b * NS + jj] = (float)mi;
      float pv = sm[OFF_SCOR + jj * SP + soli[jj]];  // sol[j] unmasked at step j
      out[NB * NS + b * NSTEPS + (jj - 1)] = pv - m - __logf(ssum);
    }
  }
}

extern "C" void kernel_launch(void* const* d_in, const int* in_sizes, int n_in,
                              void* d_out, int out_size, void* d_ws,
                              size_t ws_size, hipStream_t stream) {
  (void)in_sizes; (void)n_in; (void)out_size; (void)ws_size;
  const float* instance = (const float*)d_in[0];
  const int*   solution = (const int*)d_in[1];
  const float* Z        = (const float*)d_in[2];
  const float* IH       = (const float*)d_in[3];
  const float* last_hh  = (const float*)d_in[4];
  const float* W_emb    = (const float*)d_in[5];
  const float* b_emb    = (const float*)d_in[6];
  const float* W_ih     = (const float*)d_in[7];
  const float* W_hh     = (const float*)d_in[8];
  const float* b_ih     = (const float*)d_in[9];
  const float* b_hh     = (const float*)d_in[10];
  const float* W_a      = (const float*)d_in[11];
  const float* v_a      = (const float*)d_in[12];
  const float* W1       = (const float*)d_in[13];
  const float* b1       = (const float*)d_in[14];
  const float* W2       = (const float*)d_in[15];
  const float* b2       = (const float*)d_in[16];
  const float* Wp       = (const float*)d_in[17];
  const float* vp       = (const float*)d_in[18];
  float* out = (float*)d_out;
  float* gWf = (float*)d_ws;  // 64 KB scratch for folded MLP weight

  // pre-kernel: compute Wf once (same stream -> ordered before decoder)
  fold_kernel<<<NH, NH, 0, stream>>>(W1, W2, Wp, gWf);

  const int shmem = SM_FLOATS * 4;
  static_assert(SM_FLOATS * 4 <= 160 * 1024, "LDS overlay too big");
  hipFuncSetAttribute((const void*)decoder_kernel,
                      hipFuncAttributeMaxDynamicSharedMemorySize, shmem);
  decoder_kernel<<<NB, 512, shmem, stream>>>(
      instance, solution, Z, IH, last_hh, W_emb, b_emb, W_ih, W_hh, b_ih, b_hh,
      W_a, v_a, W1, b1, W2, b2, Wp, vp, gWf, out);
}